// Round 2
// baseline (1196.707 us; speedup 1.0000x reference)
//
#include <hip/hip_runtime.h>
#include <cstdint>
#include <cstddef>

// ============================================================================
// MAE ViT forward (B=2, enc N=1250 x2 layers, dec N=2500 x2 layers, D=768,
// H=8, HD=96, FF=2048). All big matmuls via bf16 MFMA (fp32 accum); LN,
// softmax, residuals in fp32.
// ============================================================================

#define NBATCH  2
#define NPATCH  2500
#define NVIS    1250
#define DMODEL  768
#define NHEAD   8
#define HDIM    96
#define FFDIM   2048
#define NPADV   2560   // padded N for V^T buffer

typedef __attribute__((ext_vector_type(8))) short bf16x8;
typedef __attribute__((ext_vector_type(4))) float f32x4;

__device__ __forceinline__ short f2bf(float f){
  union { float f; unsigned u; } x; x.f = f;
  unsigned r = x.u + 0x7fffu + ((x.u >> 16) & 1u);   // RNE
  return (short)(r >> 16);
}

__device__ __forceinline__ void async_copy16(void* lds, const void* g){
  __builtin_amdgcn_global_load_lds(
      (const __attribute__((address_space(1))) unsigned int*)g,
      (__attribute__((address_space(3))) unsigned int*)lds, 16, 0, 0);
}

// ---------------------------------------------------------------------------
// Batched weight transpose + bf16 cast:  src (K,N) f32  ->  dst (N,K) bf16
// ---------------------------------------------------------------------------
struct TJob { const float* src; short* dst; int K; int N; int tile_base; int tiles_x; };
struct TJobs { TJob j[17]; };

__global__ __launch_bounds__(256) void transpose_all_kernel(TJobs jobs){
  int bid = blockIdx.x;
  int ji = 0;
  #pragma unroll
  for (int k=1;k<17;k++) if (bid >= jobs.j[k].tile_base) ji = k;
  TJob jb = jobs.j[ji];
  int lt = bid - jb.tile_base;
  int tx = lt % jb.tiles_x, ty = lt / jb.tiles_x;
  __shared__ float tile[32][33];
  int lx = threadIdx.x & 31, ly = threadIdx.x >> 5;
  #pragma unroll
  for (int r=0;r<4;r++)
    tile[ly + r*8][lx] = jb.src[(size_t)(ty*32 + ly + r*8)*jb.N + tx*32 + lx];
  __syncthreads();
  #pragma unroll
  for (int r=0;r<4;r++)
    jb.dst[(size_t)(tx*32 + ly + r*8)*jb.K + ty*32 + lx] = f2bf(tile[lx][ly + r*8]);
}

// ---------------------------------------------------------------------------
// GEMM: C(M,Nc) = A(M,K)bf16 @ Wt(Nc,K)bf16^T + bias.  MODE 0: bf16 out,
// 1: f32 out, 2: bf16 out + ReLU.  128x128 tile, BK=64, 4 waves,
// global_load_lds(16B) with XOR seg-swizzle (linear dest, pre-swizzled src).
// ---------------------------------------------------------------------------
template<int MODE>
__global__ __launch_bounds__(256) void gemm_kernel(const short* __restrict__ A,
    const short* __restrict__ Wt, const float* __restrict__ bias,
    short* __restrict__ Cb, float* __restrict__ Cf, int M, int Nc, int K){
  __shared__ short ldsA[128*64];
  __shared__ short ldsB[128*64];
  const int t = threadIdx.x, w = t>>6, ln = t&63;
  const int m0 = blockIdx.x*128, n0 = blockIdx.y*128;
  const int wr = (w>>1)*64, wc = (w&1)*64;
  const f32x4 fz = {0.f,0.f,0.f,0.f};
  f32x4 acc[4][4];
  #pragma unroll
  for (int mi=0;mi<4;mi++)
    #pragma unroll
    for (int ni=0;ni<4;ni++) acc[mi][ni] = fz;
  const int nkt = K >> 6;
  for (int kt=0; kt<nkt; kt++){
    #pragma unroll
    for (int c=0;c<4;c++){
      int chunk = c*256 + t;
      int row = chunk>>3, seg = chunk&7, sgs = seg ^ (row&7);
      int gm = m0 + row; if (gm >= M) gm = M-1;           // clamp; stores masked
      async_copy16((char*)ldsA + c*4096 + w*1024, A  + (size_t)gm*K      + kt*64 + sgs*8);
      async_copy16((char*)ldsB + c*4096 + w*1024, Wt + (size_t)(n0+row)*K + kt*64 + sgs*8);
    }
    __syncthreads();                                     // drains vmcnt
    #pragma unroll
    for (int ks=0;ks<2;ks++){
      bf16x8 af[4], bfr[4];
      #pragma unroll
      for (int mi=0;mi<4;mi++){
        int r = wr + mi*16 + (ln&15);
        int d = ks*4 + (ln>>4);
        af[mi]  = *(const bf16x8*)((const char*)ldsA + r*128 + ((d^(r&7))*16));
        int cc = wc + mi*16 + (ln&15);
        bfr[mi] = *(const bf16x8*)((const char*)ldsB + cc*128 + ((d^(cc&7))*16));
      }
      #pragma unroll
      for (int mi=0;mi<4;mi++)
        #pragma unroll
        for (int ni=0;ni<4;ni++)
          acc[mi][ni] = __builtin_amdgcn_mfma_f32_16x16x32_bf16(af[mi], bfr[ni], acc[mi][ni], 0,0,0);
    }
    __syncthreads();
  }
  float bv[4];
  #pragma unroll
  for (int ni=0;ni<4;ni++) bv[ni] = bias[n0 + wc + ni*16 + (ln&15)];
  #pragma unroll
  for (int mi=0;mi<4;mi++){
    #pragma unroll
    for (int j=0;j<4;j++){
      int gr = m0 + wr + mi*16 + (ln>>4)*4 + j;
      if (gr < M){
        #pragma unroll
        for (int ni=0;ni<4;ni++){
          float v = acc[mi][ni][j] + bv[ni];
          if (MODE==2) v = fmaxf(v, 0.f);
          int gc = n0 + wc + ni*16 + (ln&15);
          if (MODE==1) Cf[(size_t)gr*Nc + gc] = v;
          else         Cb[(size_t)gr*Nc + gc] = f2bf(v);
        }
      }
    }
  }
}

// ---------------------------------------------------------------------------
// V transpose: qkv(M,2304) v-part -> vt[b][h][hd][n] (row len NPADV), zero pad
// ---------------------------------------------------------------------------
__global__ __launch_bounds__(256) void vtrans_kernel(const short* __restrict__ qkv,
    short* __restrict__ vt, int N){
  int bh = blockIdx.z;
  int b = bh >> 3, h = bh & 7;
  int n0 = blockIdx.x*32, hd0 = blockIdx.y*32;
  __shared__ short tile[32][33];
  int lx = threadIdx.x & 31, ly = threadIdx.x >> 5;
  #pragma unroll
  for (int r=0;r<4;r++){
    int n = n0 + ly + r*8;
    short val = 0;
    if (n < N) val = qkv[(size_t)(b*N+n)*2304 + 1536 + h*96 + hd0 + lx];
    tile[ly+r*8][lx] = val;
  }
  __syncthreads();
  #pragma unroll
  for (int r=0;r<4;r++){
    int hd = hd0 + ly + r*8, n = n0 + lx;
    vt[(size_t)(bh*96 + hd)*NPADV + n] = tile[lx][ly+r*8];
  }
}

// ---------------------------------------------------------------------------
// Flash attention: 64 q-rows/block, 4 waves (16 q-rows each), iterate kv tiles
// of 64.  QK^T and PV via 16x16x32 bf16 MFMA; online softmax fp32.
// LDS pads chosen for <=2-way bank conflicts (free).
// ---------------------------------------------------------------------------
__global__ __launch_bounds__(256) void attn_kernel(const short* __restrict__ qkv,
    const short* __restrict__ vt, short* __restrict__ ao, int N, int NT){
  __shared__ short Qs[64*104];
  __shared__ short Ks[64*104];
  __shared__ short Vs[96*72];
  __shared__ float Ps[4*16*68];
  const int t = threadIdx.x, w = t>>6, ln = t&63;
  const int bh = blockIdx.y, b = bh >> 3, h = bh & 7;
  const int q0 = blockIdx.x * 64;
  const float scale = 0.1020620726159658f;   // 1/sqrt(96)
  // stage Q (once)
  #pragma unroll
  for (int i=0;i<3;i++){
    int chunk = i*256 + t; int row = chunk/12, cs = chunk - row*12;
    int gn = q0 + row; if (gn >= N) gn = N-1;
    const short* gp = qkv + (size_t)(b*N+gn)*2304 + h*96 + cs*8;
    *(bf16x8*)&Qs[row*104 + cs*8] = *(const bf16x8*)gp;
  }
  __syncthreads();
  bf16x8 qf[3];
  #pragma unroll
  for (int ks=0;ks<3;ks++)
    qf[ks] = *(const bf16x8*)&Qs[(w*16 + (ln&15))*104 + (ks*4 + (ln>>4))*8];
  const f32x4 fz = {0.f,0.f,0.f,0.f};
  f32x4 o[6];
  #pragma unroll
  for (int g=0; g<6; g++) o[g] = fz;
  float mrun[4] = {-1e30f,-1e30f,-1e30f,-1e30f};
  float srun[4] = {0.f,0.f,0.f,0.f};
  for (int kt=0; kt<NT; kt++){
    int n0 = kt*64;
    #pragma unroll
    for (int i=0;i<3;i++){         // stage K
      int chunk = i*256 + t; int row = chunk/12, cs = chunk - row*12;
      int gn = n0 + row; if (gn >= N) gn = N-1;
      const short* gp = qkv + (size_t)(b*N+gn)*2304 + 768 + h*96 + cs*8;
      *(bf16x8*)&Ks[row*104 + cs*8] = *(const bf16x8*)gp;
    }
    #pragma unroll
    for (int i=0;i<3;i++){         // stage V^T (pad region is zeros)
      int chunk = i*256 + t; int row = chunk>>3, seg = chunk&7;
      const short* gp = vt + (size_t)(bh*96 + row)*NPADV + n0 + seg*8;
      *(bf16x8*)&Vs[row*72 + seg*8] = *(const bf16x8*)gp;
    }
    __syncthreads();
    f32x4 s[4];
    #pragma unroll
    for (int tt=0;tt<4;tt++){
      f32x4 sc = fz;
      #pragma unroll
      for (int ks=0;ks<3;ks++){
        bf16x8 kb = *(const bf16x8*)&Ks[(tt*16 + (ln&15))*104 + (ks*4 + (ln>>4))*8];
        sc = __builtin_amdgcn_mfma_f32_16x16x32_bf16(qf[ks], kb, sc, 0,0,0);
      }
      int col = n0 + tt*16 + (ln&15);
      float msk = (col < N) ? 0.f : -1e30f;
      #pragma unroll
      for (int j=0;j<4;j++) s[tt][j] = sc[j]*scale + msk;
    }
    #pragma unroll
    for (int j=0;j<4;j++){         // online softmax, rows (ln>>4)*4+j
      float mx = fmaxf(fmaxf(s[0][j], s[1][j]), fmaxf(s[2][j], s[3][j]));
      #pragma unroll
      for (int d=1; d<16; d<<=1) mx = fmaxf(mx, __shfl_xor(mx, d));
      float mnew = fmaxf(mrun[j], mx);
      float alpha = __expf(mrun[j] - mnew);
      mrun[j] = mnew;
      float ps = 0.f;
      #pragma unroll
      for (int tt=0;tt<4;tt++){ float pv = __expf(s[tt][j] - mnew); s[tt][j] = pv; ps += pv; }
      #pragma unroll
      for (int d=1; d<16; d<<=1) ps += __shfl_xor(ps, d);
      srun[j] = srun[j]*alpha + ps;
      #pragma unroll
      for (int g=0; g<6; g++) o[g][j] *= alpha;
    }
    // P -> per-wave LDS (wave-private; no barrier needed)
    #pragma unroll
    for (int tt=0;tt<4;tt++)
      #pragma unroll
      for (int j=0;j<4;j++)
        Ps[(w*16 + (ln>>4)*4 + j)*68 + tt*16 + (ln&15)] = s[tt][j];
    #pragma unroll
    for (int ks2=0; ks2<2; ks2++){ // PV
      const float* pr = &Ps[(w*16 + (ln&15))*68 + ks2*32 + (ln>>4)*8];
      f32x4 p0 = *(const f32x4*)pr;
      f32x4 p1 = *(const f32x4*)(pr+4);
      bf16x8 pa;
      #pragma unroll
      for (int j=0;j<4;j++){ pa[j] = f2bf(p0[j]); pa[4+j] = f2bf(p1[j]); }
      #pragma unroll
      for (int g=0; g<6; g++){
        bf16x8 vb = *(const bf16x8*)&Vs[(g*16 + (ln&15))*72 + (ks2*4 + (ln>>4))*8];
        o[g] = __builtin_amdgcn_mfma_f32_16x16x32_bf16(pa, vb, o[g], 0,0,0);
      }
    }
    __syncthreads();
  }
  float inv[4];
  #pragma unroll
  for (int j=0;j<4;j++) inv[j] = 1.f / srun[j];
  #pragma unroll
  for (int g=0; g<6; g++)
    #pragma unroll
    for (int j=0;j<4;j++){
      int qr = q0 + w*16 + (ln>>4)*4 + j;
      if (qr < N)
        ao[(size_t)(b*N+qr)*768 + h*96 + g*16 + (ln&15)] = f2bf(o[g][j]*inv[j]);
    }
}

// ---------------------------------------------------------------------------
// LayerNorm(x + add) -> f32 + bf16.  One block per row (768), 256 threads.
// ---------------------------------------------------------------------------
__global__ __launch_bounds__(256) void ln_kernel(const float* __restrict__ xin,
    const float* __restrict__ add, const float* __restrict__ g,
    const float* __restrict__ be, float* __restrict__ xo, short* __restrict__ xob){
  int row = blockIdx.x, t = threadIdx.x;
  float e[3]; float s = 0.f;
  #pragma unroll
  for (int k=0;k<3;k++){
    size_t off = (size_t)row*768 + t + k*256;
    e[k] = xin[off] + add[off]; s += e[k];
  }
  #pragma unroll
  for (int d=32; d; d>>=1) s += __shfl_xor(s, d);
  __shared__ float red[8];
  if ((t&63)==0) red[t>>6] = s;
  __syncthreads();
  float mean = (red[0]+red[1]+red[2]+red[3]) * (1.f/768.f);
  float vs = 0.f;
  #pragma unroll
  for (int k=0;k<3;k++){ float dd = e[k]-mean; vs += dd*dd; }
  #pragma unroll
  for (int d=32; d; d>>=1) vs += __shfl_xor(vs, d);
  if ((t&63)==0) red[4 + (t>>6)] = vs;
  __syncthreads();
  float rstd = rsqrtf((red[4]+red[5]+red[6]+red[7]) * (1.f/768.f) + 1e-5f);
  #pragma unroll
  for (int k=0;k<3;k++){
    int c = t + k*256;
    size_t off = (size_t)row*768 + c;
    float ov = (e[k]-mean)*rstd*g[c] + be[c];
    xo[off] = ov; xob[off] = f2bf(ov);
  }
}

// ---------------------------------------------------------------------------
// patchify + gather visible + enc_pos
// ---------------------------------------------------------------------------
__global__ __launch_bounds__(256) void patchify_kernel(const float* __restrict__ x,
    const int* __restrict__ vis, const float* __restrict__ enc_pos,
    float* __restrict__ xe, short* __restrict__ xeb){
  int b = blockIdx.y, i = blockIdx.x;
  int pidx = vis[b*NVIS + i];
  int gy = pidx / 50, gx = pidx - gy*50;
  #pragma unroll
  for (int k=0;k<3;k++){
    int d = threadIdx.x + k*256;
    int c = d >> 8, rr = d & 255, py = rr >> 4, px = rr & 15;
    float v = x[(((size_t)b*3 + c)*800 + gy*16 + py)*800 + gx*16 + px]
            + enc_pos[(size_t)i*768 + d];
    size_t off = (size_t)(b*NVIS + i)*768 + d;
    xe[off] = v; xeb[off] = f2bf(v);
  }
}

// rank(p) = #{j : vis[j] < p}  (reproduces full.at[b, sort(vis)].set(h))
__global__ __launch_bounds__(256) void rank_kernel(const int* __restrict__ vis,
    int* __restrict__ rnk){
  int b = blockIdx.y; int i = blockIdx.x*256 + threadIdx.x;
  if (i >= NVIS) return;
  int p = vis[b*NVIS + i]; int c = 0;
  for (int j=0;j<NVIS;j++) c += (vis[b*NVIS + j] < p) ? 1 : 0;
  rnk[b*NVIS + i] = c;
}

__global__ __launch_bounds__(256) void dec_init_kernel(const float* __restrict__ mask_token,
    const float* __restrict__ dec_pos, float* __restrict__ xd, short* __restrict__ xdb){
  int row = blockIdx.x;                 // b*2500 + p
  int p = row % NPATCH;
  #pragma unroll
  for (int k=0;k<3;k++){
    int c = threadIdx.x + k*256;
    float v = mask_token[c] + dec_pos[(size_t)p*768 + c];
    size_t off = (size_t)row*768 + c;
    xd[off] = v; xdb[off] = f2bf(v);
  }
}

__global__ __launch_bounds__(256) void scatter_kernel(const int* __restrict__ vis,
    const int* __restrict__ rnk, const float* __restrict__ xe,
    const float* __restrict__ dec_pos, float* __restrict__ xd, short* __restrict__ xdb){
  int b = blockIdx.y, i = blockIdx.x;
  int p = vis[b*NVIS+i]; int r = rnk[b*NVIS+i];
  #pragma unroll
  for (int k=0;k<3;k++){
    int c = threadIdx.x + k*256;
    float v = xe[(size_t)(b*NVIS + r)*768 + c] + dec_pos[(size_t)p*768 + c];
    size_t off = (size_t)(b*NPATCH + p)*768 + c;
    xd[off] = v; xdb[off] = f2bf(v);
  }
}

// ---------------------------------------------------------------------------
// host side
// ---------------------------------------------------------------------------
static void run_block(hipStream_t stream, float* xf, short* xb, int M, int N, int NT,
                      const short* wqkvT, const float* qkv_b, const short* woutT,
                      const float* out_b, const short* w1T, const float* b1,
                      const short* w2T, const float* b2,
                      const float* g1, const float* be1, const float* g2, const float* be2,
                      short* qkvb, short* vt, short* aob, short* ffnb, float* tmp){
  int mt = (M + 127)/128;
  gemm_kernel<0><<<dim3(mt, 18), 256, 0, stream>>>(xb, wqkvT, qkv_b, qkvb, nullptr, M, 2304, 768);
  vtrans_kernel<<<dim3(NT*2, 3, 16), 256, 0, stream>>>(qkvb, vt, N);
  attn_kernel<<<dim3(NT, 16), 256, 0, stream>>>(qkvb, vt, aob, N, NT);
  gemm_kernel<1><<<dim3(mt, 6), 256, 0, stream>>>(aob, woutT, out_b, nullptr, tmp, M, 768, 768);
  ln_kernel<<<M, 256, 0, stream>>>(xf, tmp, g1, be1, xf, xb);
  gemm_kernel<2><<<dim3(mt, 16), 256, 0, stream>>>(xb, w1T, b1, ffnb, nullptr, M, 2048, 768);
  gemm_kernel<1><<<dim3(mt, 6), 256, 0, stream>>>(ffnb, w2T, b2, nullptr, tmp, M, 768, 2048);
  ln_kernel<<<M, 256, 0, stream>>>(xf, tmp, g2, be2, xf, xb);
}

extern "C" void kernel_launch(void* const* d_in, const int* in_sizes, int n_in,
                              void* d_out, int out_size, void* d_ws, size_t ws_size,
                              hipStream_t stream){
  const float* x        = (const float*)d_in[0];
  const int*   vis      = (const int*)d_in[1];
  const float* eqkv_w   = (const float*)d_in[3];
  const float* eqkv_b   = (const float*)d_in[4];
  const float* eout_w   = (const float*)d_in[5];
  const float* eout_b   = (const float*)d_in[6];
  const float* ew1      = (const float*)d_in[7];
  const float* eb1      = (const float*)d_in[8];
  const float* ew2      = (const float*)d_in[9];
  const float* eb2      = (const float*)d_in[10];
  const float* eg1      = (const float*)d_in[11];
  const float* ebe1     = (const float*)d_in[12];
  const float* eg2      = (const float*)d_in[13];
  const float* ebe2     = (const float*)d_in[14];
  const float* dqkv_w   = (const float*)d_in[15];
  const float* dqkv_b   = (const float*)d_in[16];
  const float* dout_w   = (const float*)d_in[17];
  const float* dout_b   = (const float*)d_in[18];
  const float* dw1      = (const float*)d_in[19];
  const float* db1      = (const float*)d_in[20];
  const float* dw2      = (const float*)d_in[21];
  const float* db2      = (const float*)d_in[22];
  const float* dg1      = (const float*)d_in[23];
  const float* dbe1     = (const float*)d_in[24];
  const float* dg2      = (const float*)d_in[25];
  const float* dbe2     = (const float*)d_in[26];
  const float* fout_w   = (const float*)d_in[27];
  const float* fout_b   = (const float*)d_in[28];
  const float* mask_tok = (const float*)d_in[29];
  const float* enc_posp = (const float*)d_in[30];
  const float* dec_posp = (const float*)d_in[31];

  char* p = (char*)d_ws;
  auto alloc = [&](size_t bytes)->char*{ char* r = p; p += (bytes + 255) & ~(size_t)255; return r; };

  const float* qkvw_s[2] = {eqkv_w, dqkv_w};
  const float* outw_s[2] = {eout_w, dout_w};
  const float* w1_s[2]   = {ew1, dw1};
  const float* w2_s[2]   = {ew2, dw2};

  short *wq[2][2], *wo[2][2], *w1t[2][2], *w2t[2][2];
  TJobs jobs; int jidx = 0; int tbase = 0;
  auto addJob = [&](const float* src, short* dst, int K, int N){
    jobs.j[jidx].src = src; jobs.j[jidx].dst = dst; jobs.j[jidx].K = K; jobs.j[jidx].N = N;
    jobs.j[jidx].tile_base = tbase; jobs.j[jidx].tiles_x = N/32;
    tbase += (K/32)*(N/32); jidx++;
  };
  for (int s=0;s<2;s++)
    for (int i=0;i<2;i++){
      wq[s][i]  = (short*)alloc((size_t)2304*768*2);
      addJob(qkvw_s[s] + (size_t)i*768*2304, wq[s][i], 768, 2304);
      wo[s][i]  = (short*)alloc((size_t)768*768*2);
      addJob(outw_s[s] + (size_t)i*768*768, wo[s][i], 768, 768);
      w1t[s][i] = (short*)alloc((size_t)2048*768*2);
      addJob(w1_s[s] + (size_t)i*768*2048, w1t[s][i], 768, 2048);
      w2t[s][i] = (short*)alloc((size_t)768*2048*2);
      addJob(w2_s[s] + (size_t)i*2048*768, w2t[s][i], 2048, 768);
    }
  short* wfin = (short*)alloc((size_t)768*768*2);
  addJob(fout_w, wfin, 768, 768);
  int total_tiles = tbase;   // 22080

  float* xe   = (float*)alloc((size_t)2500*768*4);
  short* xeb  = (short*)alloc((size_t)2500*768*2);
  float* xd   = (float*)alloc((size_t)5000*768*4);
  short* xdb  = (short*)alloc((size_t)5000*768*2);
  short* qkvb = (short*)alloc((size_t)5000*2304*2);
  short* vt   = (short*)alloc((size_t)16*96*NPADV*2);
  short* aob  = (short*)alloc((size_t)5000*768*2);
  short* ffnb = (short*)alloc((size_t)5000*2048*2);
  float* tmp  = (float*)alloc((size_t)5000*768*4);
  int*   rnk  = (int*)alloc((size_t)2*NVIS*4);

  transpose_all_kernel<<<total_tiles, 256, 0, stream>>>(jobs);
  patchify_kernel<<<dim3(NVIS, NBATCH), 256, 0, stream>>>(x, vis, enc_posp, xe, xeb);
  rank_kernel<<<dim3((NVIS+255)/256, NBATCH), 256, 0, stream>>>(vis, rnk);

  for (int i=0;i<2;i++)
    run_block(stream, xe, xeb, 2500, 1250, 20,
              wq[0][i], eqkv_b + i*2304, wo[0][i], eout_b + i*768,
              w1t[0][i], eb1 + i*2048, w2t[0][i], eb2 + i*768,
              eg1 + i*768, ebe1 + i*768, eg2 + i*768, ebe2 + i*768,
              qkvb, vt, aob, ffnb, tmp);

  dec_init_kernel<<<NBATCH*NPATCH, 256, 0, stream>>>(mask_tok, dec_posp, xd, xdb);
  scatter_kernel<<<dim3(NVIS, NBATCH), 256, 0, stream>>>(vis, rnk, xe, dec_posp, xd, xdb);

  for (int i=0;i<2;i++)
    run_block(stream, xd, xdb, 5000, 2500, 40,
              wq[1][i], dqkv_b + i*2304, wo[1][i], dout_b + i*768,
              w1t[1][i], db1 + i*2048, w2t[1][i], db2 + i*768,
              dg1 + i*768, dbe1 + i*768, dg2 + i*768, dbe2 + i*768,
              qkvb, vt, aob, ffnb, tmp);

  gemm_kernel<1><<<dim3(40, 6), 256, 0, stream>>>(xdb, wfin, fout_b, nullptr,
                                                  (float*)d_out, 5000, 768, 768);
}

// Round 3
// 1100.065 us; speedup vs baseline: 1.0879x; 1.0879x over previous
//
#include <hip/hip_runtime.h>
#include <cstdint>
#include <cstddef>

// ============================================================================
// MAE ViT forward (B=2, enc N=1250 x2 layers, dec N=2500 x2 layers, D=768,
// H=8, HD=96, FF=2048). All big matmuls via bf16 MFMA (fp32 accum); LN,
// softmax, residuals in fp32.
// R3: attention rewrite — gload_lds K/V staging w/ XOR swizzle, Q direct to
// regs, bf16 Ps, exp2 softmax, defer-max, deferred l-sum, setprio.
// ============================================================================

#define NBATCH  2
#define NPATCH  2500
#define NVIS    1250
#define DMODEL  768
#define NHEAD   8
#define HDIM    96
#define FFDIM   2048
#define NPADV   2560   // padded N for V^T buffer

typedef __attribute__((ext_vector_type(8))) short bf16x8;
typedef __attribute__((ext_vector_type(4))) float f32x4;

__device__ __forceinline__ short f2bf(float f){
  union { float f; unsigned u; } x; x.f = f;
  unsigned r = x.u + 0x7fffu + ((x.u >> 16) & 1u);   // RNE
  return (short)(r >> 16);
}

__device__ __forceinline__ void async_copy16(void* lds, const void* g){
  __builtin_amdgcn_global_load_lds(
      (const __attribute__((address_space(1))) unsigned int*)g,
      (__attribute__((address_space(3))) unsigned int*)lds, 16, 0, 0);
}

// ---------------------------------------------------------------------------
// Batched weight transpose + bf16 cast:  src (K,N) f32  ->  dst (N,K) bf16
// ---------------------------------------------------------------------------
struct TJob { const float* src; short* dst; int K; int N; int tile_base; int tiles_x; };
struct TJobs { TJob j[17]; };

__global__ __launch_bounds__(256) void transpose_all_kernel(TJobs jobs){
  int bid = blockIdx.x;
  int ji = 0;
  #pragma unroll
  for (int k=1;k<17;k++) if (bid >= jobs.j[k].tile_base) ji = k;
  TJob jb = jobs.j[ji];
  int lt = bid - jb.tile_base;
  int tx = lt % jb.tiles_x, ty = lt / jb.tiles_x;
  __shared__ float tile[32][33];
  int lx = threadIdx.x & 31, ly = threadIdx.x >> 5;
  #pragma unroll
  for (int r=0;r<4;r++)
    tile[ly + r*8][lx] = jb.src[(size_t)(ty*32 + ly + r*8)*jb.N + tx*32 + lx];
  __syncthreads();
  #pragma unroll
  for (int r=0;r<4;r++)
    jb.dst[(size_t)(tx*32 + ly + r*8)*jb.K + ty*32 + lx] = f2bf(tile[lx][ly + r*8]);
}

// ---------------------------------------------------------------------------
// GEMM: C(M,Nc) = A(M,K)bf16 @ Wt(Nc,K)bf16^T + bias.  MODE 0: bf16 out,
// 1: f32 out, 2: bf16 out + ReLU.  128x128 tile, BK=64, 4 waves,
// global_load_lds(16B) with XOR seg-swizzle (linear dest, pre-swizzled src).
// ---------------------------------------------------------------------------
template<int MODE>
__global__ __launch_bounds__(256) void gemm_kernel(const short* __restrict__ A,
    const short* __restrict__ Wt, const float* __restrict__ bias,
    short* __restrict__ Cb, float* __restrict__ Cf, int M, int Nc, int K){
  __shared__ short ldsA[128*64];
  __shared__ short ldsB[128*64];
  const int t = threadIdx.x, w = t>>6, ln = t&63;
  const int m0 = blockIdx.x*128, n0 = blockIdx.y*128;
  const int wr = (w>>1)*64, wc = (w&1)*64;
  const f32x4 fz = {0.f,0.f,0.f,0.f};
  f32x4 acc[4][4];
  #pragma unroll
  for (int mi=0;mi<4;mi++)
    #pragma unroll
    for (int ni=0;ni<4;ni++) acc[mi][ni] = fz;
  const int nkt = K >> 6;
  for (int kt=0; kt<nkt; kt++){
    #pragma unroll
    for (int c=0;c<4;c++){
      int chunk = c*256 + t;
      int row = chunk>>3, seg = chunk&7, sgs = seg ^ (row&7);
      int gm = m0 + row; if (gm >= M) gm = M-1;           // clamp; stores masked
      async_copy16((char*)ldsA + c*4096 + w*1024, A  + (size_t)gm*K      + kt*64 + sgs*8);
      async_copy16((char*)ldsB + c*4096 + w*1024, Wt + (size_t)(n0+row)*K + kt*64 + sgs*8);
    }
    __syncthreads();                                     // drains vmcnt
    #pragma unroll
    for (int ks=0;ks<2;ks++){
      bf16x8 af[4], bfr[4];
      #pragma unroll
      for (int mi=0;mi<4;mi++){
        int r = wr + mi*16 + (ln&15);
        int d = ks*4 + (ln>>4);
        af[mi]  = *(const bf16x8*)((const char*)ldsA + r*128 + ((d^(r&7))*16));
        int cc = wc + mi*16 + (ln&15);
        bfr[mi] = *(const bf16x8*)((const char*)ldsB + cc*128 + ((d^(cc&7))*16));
      }
      #pragma unroll
      for (int mi=0;mi<4;mi++)
        #pragma unroll
        for (int ni=0;ni<4;ni++)
          acc[mi][ni] = __builtin_amdgcn_mfma_f32_16x16x32_bf16(af[mi], bfr[ni], acc[mi][ni], 0,0,0);
    }
    __syncthreads();
  }
  float bv[4];
  #pragma unroll
  for (int ni=0;ni<4;ni++) bv[ni] = bias[n0 + wc + ni*16 + (ln&15)];
  #pragma unroll
  for (int mi=0;mi<4;mi++){
    #pragma unroll
    for (int j=0;j<4;j++){
      int gr = m0 + wr + mi*16 + (ln>>4)*4 + j;
      if (gr < M){
        #pragma unroll
        for (int ni=0;ni<4;ni++){
          float v = acc[mi][ni][j] + bv[ni];
          if (MODE==2) v = fmaxf(v, 0.f);
          int gc = n0 + wc + ni*16 + (ln&15);
          if (MODE==1) Cf[(size_t)gr*Nc + gc] = v;
          else         Cb[(size_t)gr*Nc + gc] = f2bf(v);
        }
      }
    }
  }
}

// ---------------------------------------------------------------------------
// V transpose: qkv(M,2304) v-part -> vt[b][h][hd][n] (row len NPADV), zero pad
// ---------------------------------------------------------------------------
__global__ __launch_bounds__(256) void vtrans_kernel(const short* __restrict__ qkv,
    short* __restrict__ vt, int N){
  int bh = blockIdx.z;
  int b = bh >> 3, h = bh & 7;
  int n0 = blockIdx.x*32, hd0 = blockIdx.y*32;
  __shared__ short tile[32][33];
  int lx = threadIdx.x & 31, ly = threadIdx.x >> 5;
  #pragma unroll
  for (int r=0;r<4;r++){
    int n = n0 + ly + r*8;
    short val = 0;
    if (n < N) val = qkv[(size_t)(b*N+n)*2304 + 1536 + h*96 + hd0 + lx];
    tile[ly+r*8][lx] = val;
  }
  __syncthreads();
  #pragma unroll
  for (int r=0;r<4;r++){
    int hd = hd0 + ly + r*8, n = n0 + lx;
    vt[(size_t)(bh*96 + hd)*NPADV + n] = tile[lx][ly+r*8];
  }
}

// ---------------------------------------------------------------------------
// Flash attention R3: 64 q-rows/block, 4 waves (16 q-rows each).
// Q -> registers directly.  K: LDS [64][16 segs] (12 real, XOR-swizzled,
// gload_lds).  V^T: LDS [96][8 segs] (XOR-swizzled, gload_lds).  P: bf16 LDS
// per-wave [16][72].  exp2-domain softmax, defer-max (THR=11.5 log2),
// l-sum deferred to end.  LDS = 37.9KB -> 4 blocks/CU capacity.
// ---------------------------------------------------------------------------
__global__ __launch_bounds__(256) void attn_kernel(const short* __restrict__ qkv,
    const short* __restrict__ vt, short* __restrict__ ao, int N, int NT){
  __shared__ short Ks[64*128];   // 64 rows x 16 segs x 8 shorts (swizzled)
  __shared__ short Vs[96*64];    // 96 rows x  8 segs x 8 shorts (swizzled)
  __shared__ short Ps[4*16*72];  // per-wave bf16 P, row stride 72
  const int t = threadIdx.x, w = t>>6, ln = t&63;
  const int col = ln & 15, hi = ln >> 4;
  const int bh = blockIdx.y, b = bh >> 3, h = bh & 7;
  const int q0 = blockIdx.x * 64;
  short* Pw = &Ps[w*16*72];
  const float scale2 = 0.14724974f;   // (1/sqrt(96)) * log2(e)

  // Q fragments straight from global (A-frag: row=col, k=(ks*4+hi)*8..+8)
  bf16x8 qf[3];
  {
    int gq = q0 + w*16 + col; if (gq >= N) gq = N-1;
    const short* qrow = qkv + (size_t)(b*N+gq)*2304 + h*96;
    #pragma unroll
    for (int ks=0;ks<3;ks++)
      qf[ks] = *(const bf16x8*)(qrow + ks*32 + hi*8);
  }
  const f32x4 fz = {0.f,0.f,0.f,0.f};
  f32x4 o[6];
  #pragma unroll
  for (int g=0; g<6; g++) o[g] = fz;
  float mrun[4] = {-3e38f,-3e38f,-3e38f,-3e38f};
  float srun[4] = {0.f,0.f,0.f,0.f};

  for (int kt=0; kt<NT; kt++){
    int n0 = kt*64;
    #pragma unroll
    for (int i=0;i<4;i++){         // stage K (16 segs; segs 12-15 dummy)
      int chunk = i*256 + t, row = chunk>>4, seg = chunk&15;
      int s2 = seg ^ (row&7);
      int gn = n0 + row; if (gn >= N) gn = N-1;
      const short* src = qkv + (size_t)(b*N+gn)*2304 + 768 + h*96
                       + ((s2 < 12) ? s2*8 : 0);
      async_copy16((char*)Ks + i*4096 + w*1024, src);
    }
    #pragma unroll
    for (int i=0;i<3;i++){         // stage V^T
      int chunk = i*256 + t, row = chunk>>3, seg = chunk&7;
      int s2 = seg ^ (row&7);
      const short* src = vt + (size_t)(bh*96 + row)*NPADV + n0 + s2*8;
      async_copy16((char*)Vs + i*4096 + w*1024, src);
    }
    __syncthreads();               // drains vmcnt

    f32x4 s[4];
    __builtin_amdgcn_s_setprio(1);
    #pragma unroll
    for (int tt=0;tt<4;tt++){
      f32x4 sc = fz;
      #pragma unroll
      for (int ks=0;ks<3;ks++){
        int r = tt*16 + col, d = ks*4 + hi;
        bf16x8 kb = *(const bf16x8*)((const char*)Ks + r*256 + ((d ^ (r&7))*16));
        sc = __builtin_amdgcn_mfma_f32_16x16x32_bf16(qf[ks], kb, sc, 0,0,0);
      }
      s[tt] = sc;
    }
    __builtin_amdgcn_s_setprio(0);

    #pragma unroll
    for (int tt=0;tt<4;tt++){
      float msk = (n0 + tt*16 + col < N) ? 0.f : -3e38f;
      #pragma unroll
      for (int j=0;j<4;j++) s[tt][j] = s[tt][j]*scale2 + msk;
    }
    // row max (16-lane col-group reduce), defer-max decision
    float mx[4]; bool exc = false;
    #pragma unroll
    for (int j=0;j<4;j++){
      float m0 = fmaxf(fmaxf(s[0][j], s[1][j]), fmaxf(s[2][j], s[3][j]));
      #pragma unroll
      for (int d=1; d<16; d<<=1) m0 = fmaxf(m0, __shfl_xor(m0, d));
      mx[j] = m0;
      exc = exc || (m0 > mrun[j] + 11.5f);
    }
    if (__any((int)exc)){
      #pragma unroll
      for (int j=0;j<4;j++){
        float mnew = fmaxf(mrun[j], mx[j]);
        float a = exp2f(mrun[j] - mnew);
        mrun[j] = mnew; srun[j] *= a;
        #pragma unroll
        for (int g=0; g<6; g++) o[g][j] *= a;
      }
    }
    #pragma unroll
    for (int j=0;j<4;j++){
      float ps = 0.f;
      #pragma unroll
      for (int tt=0;tt<4;tt++){ float pv = exp2f(s[tt][j] - mrun[j]); s[tt][j] = pv; ps += pv; }
      srun[j] += ps;               // per-lane partial; reduced after kv loop
      #pragma unroll
      for (int tt=0;tt<4;tt++)
        Pw[(hi*4+j)*72 + tt*16 + col] = f2bf(s[tt][j]);
    }
    // PV (P read back as A-frag from bf16 LDS; V^T swizzled b128 reads)
    __builtin_amdgcn_s_setprio(1);
    #pragma unroll
    for (int ks2=0; ks2<2; ks2++){
      bf16x8 pa = *(const bf16x8*)&Pw[col*72 + (ks2*4 + hi)*8];
      #pragma unroll
      for (int g=0; g<6; g++){
        int r = g*16 + col, d = ks2*4 + hi;
        bf16x8 vb = *(const bf16x8*)((const char*)Vs + r*128 + ((d ^ (r&7))*16));
        o[g] = __builtin_amdgcn_mfma_f32_16x16x32_bf16(pa, vb, o[g], 0,0,0);
      }
    }
    __builtin_amdgcn_s_setprio(0);
    __syncthreads();
  }
  float inv[4];
  #pragma unroll
  for (int j=0;j<4;j++){
    float ssum = srun[j];
    #pragma unroll
    for (int d=1; d<16; d<<=1) ssum += __shfl_xor(ssum, d);
    inv[j] = 1.f / ssum;
  }
  #pragma unroll
  for (int g=0; g<6; g++)
    #pragma unroll
    for (int j=0;j<4;j++){
      int qr = q0 + w*16 + hi*4 + j;
      if (qr < N)
        ao[(size_t)(b*N+qr)*768 + h*96 + g*16 + col] = f2bf(o[g][j]*inv[j]);
    }
}

// ---------------------------------------------------------------------------
// LayerNorm(x + add) -> f32 + bf16.  One block per row (768), 256 threads.
// ---------------------------------------------------------------------------
__global__ __launch_bounds__(256) void ln_kernel(const float* __restrict__ xin,
    const float* __restrict__ add, const float* __restrict__ g,
    const float* __restrict__ be, float* __restrict__ xo, short* __restrict__ xob){
  int row = blockIdx.x, t = threadIdx.x;
  float e[3]; float s = 0.f;
  #pragma unroll
  for (int k=0;k<3;k++){
    size_t off = (size_t)row*768 + t + k*256;
    e[k] = xin[off] + add[off]; s += e[k];
  }
  #pragma unroll
  for (int d=32; d; d>>=1) s += __shfl_xor(s, d);
  __shared__ float red[8];
  if ((t&63)==0) red[t>>6] = s;
  __syncthreads();
  float mean = (red[0]+red[1]+red[2]+red[3]) * (1.f/768.f);
  float vs = 0.f;
  #pragma unroll
  for (int k=0;k<3;k++){ float dd = e[k]-mean; vs += dd*dd; }
  #pragma unroll
  for (int d=32; d; d>>=1) vs += __shfl_xor(vs, d);
  if ((t&63)==0) red[4 + (t>>6)] = vs;
  __syncthreads();
  float rstd = rsqrtf((red[4]+red[5]+red[6]+red[7]) * (1.f/768.f) + 1e-5f);
  #pragma unroll
  for (int k=0;k<3;k++){
    int c = t + k*256;
    size_t off = (size_t)row*768 + c;
    float ov = (e[k]-mean)*rstd*g[c] + be[c];
    xo[off] = ov; xob[off] = f2bf(ov);
  }
}

// ---------------------------------------------------------------------------
// patchify + gather visible + enc_pos
// ---------------------------------------------------------------------------
__global__ __launch_bounds__(256) void patchify_kernel(const float* __restrict__ x,
    const int* __restrict__ vis, const float* __restrict__ enc_pos,
    float* __restrict__ xe, short* __restrict__ xeb){
  int b = blockIdx.y, i = blockIdx.x;
  int pidx = vis[b*NVIS + i];
  int gy = pidx / 50, gx = pidx - gy*50;
  #pragma unroll
  for (int k=0;k<3;k++){
    int d = threadIdx.x + k*256;
    int c = d >> 8, rr = d & 255, py = rr >> 4, px = rr & 15;
    float v = x[(((size_t)b*3 + c)*800 + gy*16 + py)*800 + gx*16 + px]
            + enc_pos[(size_t)i*768 + d];
    size_t off = (size_t)(b*NVIS + i)*768 + d;
    xe[off] = v; xeb[off] = f2bf(v);
  }
}

// rank(p) = #{j : vis[j] < p}  (reproduces full.at[b, sort(vis)].set(h))
__global__ __launch_bounds__(256) void rank_kernel(const int* __restrict__ vis,
    int* __restrict__ rnk){
  int b = blockIdx.y; int i = blockIdx.x*256 + threadIdx.x;
  if (i >= NVIS) return;
  int p = vis[b*NVIS + i]; int c = 0;
  for (int j=0;j<NVIS;j++) c += (vis[b*NVIS + j] < p) ? 1 : 0;
  rnk[b*NVIS + i] = c;
}

__global__ __launch_bounds__(256) void dec_init_kernel(const float* __restrict__ mask_token,
    const float* __restrict__ dec_pos, float* __restrict__ xd, short* __restrict__ xdb){
  int row = blockIdx.x;                 // b*2500 + p
  int p = row % NPATCH;
  #pragma unroll
  for (int k=0;k<3;k++){
    int c = threadIdx.x + k*256;
    float v = mask_token[c] + dec_pos[(size_t)p*768 + c];
    size_t off = (size_t)row*768 + c;
    xd[off] = v; xdb[off] = f2bf(v);
  }
}

__global__ __launch_bounds__(256) void scatter_kernel(const int* __restrict__ vis,
    const int* __restrict__ rnk, const float* __restrict__ xe,
    const float* __restrict__ dec_pos, float* __restrict__ xd, short* __restrict__ xdb){
  int b = blockIdx.y, i = blockIdx.x;
  int p = vis[b*NVIS+i]; int r = rnk[b*NVIS+i];
  #pragma unroll
  for (int k=0;k<3;k++){
    int c = threadIdx.x + k*256;
    float v = xe[(size_t)(b*NVIS + r)*768 + c] + dec_pos[(size_t)p*768 + c];
    size_t off = (size_t)(b*NPATCH + p)*768 + c;
    xd[off] = v; xdb[off] = f2bf(v);
  }
}

// ---------------------------------------------------------------------------
// host side
// ---------------------------------------------------------------------------
static void run_block(hipStream_t stream, float* xf, short* xb, int M, int N, int NT,
                      const short* wqkvT, const float* qkv_b, const short* woutT,
                      const float* out_b, const short* w1T, const float* b1,
                      const short* w2T, const float* b2,
                      const float* g1, const float* be1, const float* g2, const float* be2,
                      short* qkvb, short* vt, short* aob, short* ffnb, float* tmp){
  int mt = (M + 127)/128;
  gemm_kernel<0><<<dim3(mt, 18), 256, 0, stream>>>(xb, wqkvT, qkv_b, qkvb, nullptr, M, 2304, 768);
  vtrans_kernel<<<dim3(NT*2, 3, 16), 256, 0, stream>>>(qkvb, vt, N);
  attn_kernel<<<dim3(NT, 16), 256, 0, stream>>>(qkvb, vt, aob, N, NT);
  gemm_kernel<1><<<dim3(mt, 6), 256, 0, stream>>>(aob, woutT, out_b, nullptr, tmp, M, 768, 768);
  ln_kernel<<<M, 256, 0, stream>>>(xf, tmp, g1, be1, xf, xb);
  gemm_kernel<2><<<dim3(mt, 16), 256, 0, stream>>>(xb, w1T, b1, ffnb, nullptr, M, 2048, 768);
  gemm_kernel<1><<<dim3(mt, 6), 256, 0, stream>>>(ffnb, w2T, b2, nullptr, tmp, M, 768, 2048);
  ln_kernel<<<M, 256, 0, stream>>>(xf, tmp, g2, be2, xf, xb);
}

extern "C" void kernel_launch(void* const* d_in, const int* in_sizes, int n_in,
                              void* d_out, int out_size, void* d_ws, size_t ws_size,
                              hipStream_t stream){
  const float* x        = (const float*)d_in[0];
  const int*   vis      = (const int*)d_in[1];
  const float* eqkv_w   = (const float*)d_in[3];
  const float* eqkv_b   = (const float*)d_in[4];
  const float* eout_w   = (const float*)d_in[5];
  const float* eout_b   = (const float*)d_in[6];
  const float* ew1      = (const float*)d_in[7];
  const float* eb1      = (const float*)d_in[8];
  const float* ew2      = (const float*)d_in[9];
  const float* eb2      = (const float*)d_in[10];
  const float* eg1      = (const float*)d_in[11];
  const float* ebe1     = (const float*)d_in[12];
  const float* eg2      = (const float*)d_in[13];
  const float* ebe2     = (const float*)d_in[14];
  const float* dqkv_w   = (const float*)d_in[15];
  const float* dqkv_b   = (const float*)d_in[16];
  const float* dout_w   = (const float*)d_in[17];
  const float* dout_b   = (const float*)d_in[18];
  const float* dw1      = (const float*)d_in[19];
  const float* db1      = (const float*)d_in[20];
  const float* dw2      = (const float*)d_in[21];
  const float* db2      = (const float*)d_in[22];
  const float* dg1      = (const float*)d_in[23];
  const float* dbe1     = (const float*)d_in[24];
  const float* dg2      = (const float*)d_in[25];
  const float* dbe2     = (const float*)d_in[26];
  const float* fout_w   = (const float*)d_in[27];
  const float* fout_b   = (const float*)d_in[28];
  const float* mask_tok = (const float*)d_in[29];
  const float* enc_posp = (const float*)d_in[30];
  const float* dec_posp = (const float*)d_in[31];

  char* p = (char*)d_ws;
  auto alloc = [&](size_t bytes)->char*{ char* r = p; p += (bytes + 255) & ~(size_t)255; return r; };

  const float* qkvw_s[2] = {eqkv_w, dqkv_w};
  const float* outw_s[2] = {eout_w, dout_w};
  const float* w1_s[2]   = {ew1, dw1};
  const float* w2_s[2]   = {ew2, dw2};

  short *wq[2][2], *wo[2][2], *w1t[2][2], *w2t[2][2];
  TJobs jobs; int jidx = 0; int tbase = 0;
  auto addJob = [&](const float* src, short* dst, int K, int N){
    jobs.j[jidx].src = src; jobs.j[jidx].dst = dst; jobs.j[jidx].K = K; jobs.j[jidx].N = N;
    jobs.j[jidx].tile_base = tbase; jobs.j[jidx].tiles_x = N/32;
    tbase += (K/32)*(N/32); jidx++;
  };
  for (int s=0;s<2;s++)
    for (int i=0;i<2;i++){
      wq[s][i]  = (short*)alloc((size_t)2304*768*2);
      addJob(qkvw_s[s] + (size_t)i*768*2304, wq[s][i], 768, 2304);
      wo[s][i]  = (short*)alloc((size_t)768*768*2);
      addJob(outw_s[s] + (size_t)i*768*768, wo[s][i], 768, 768);
      w1t[s][i] = (short*)alloc((size_t)2048*768*2);
      addJob(w1_s[s] + (size_t)i*768*2048, w1t[s][i], 768, 2048);
      w2t[s][i] = (short*)alloc((size_t)768*2048*2);
      addJob(w2_s[s] + (size_t)i*2048*768, w2t[s][i], 2048, 768);
    }
  short* wfin = (short*)alloc((size_t)768*768*2);
  addJob(fout_w, wfin, 768, 768);
  int total_tiles = tbase;   // 22080

  float* xe   = (float*)alloc((size_t)2500*768*4);
  short* xeb  = (short*)alloc((size_t)2500*768*2);
  float* xd   = (float*)alloc((size_t)5000*768*4);
  short* xdb  = (short*)alloc((size_t)5000*768*2);
  short* qkvb = (short*)alloc((size_t)5000*2304*2);
  short* vt   = (short*)alloc((size_t)16*96*NPADV*2);
  short* aob  = (short*)alloc((size_t)5000*768*2);
  short* ffnb = (short*)alloc((size_t)5000*2048*2);
  float* tmp  = (float*)alloc((size_t)5000*768*4);
  int*   rnk  = (int*)alloc((size_t)2*NVIS*4);

  transpose_all_kernel<<<total_tiles, 256, 0, stream>>>(jobs);
  patchify_kernel<<<dim3(NVIS, NBATCH), 256, 0, stream>>>(x, vis, enc_posp, xe, xeb);
  rank_kernel<<<dim3((NVIS+255)/256, NBATCH), 256, 0, stream>>>(vis, rnk);

  for (int i=0;i<2;i++)
    run_block(stream, xe, xeb, 2500, 1250, 20,
              wq[0][i], eqkv_b + i*2304, wo[0][i], eout_b + i*768,
              w1t[0][i], eb1 + i*2048, w2t[0][i], eb2 + i*768,
              eg1 + i*768, ebe1 + i*768, eg2 + i*768, ebe2 + i*768,
              qkvb, vt, aob, ffnb, tmp);

  dec_init_kernel<<<NBATCH*NPATCH, 256, 0, stream>>>(mask_tok, dec_posp, xd, xdb);
  scatter_kernel<<<dim3(NVIS, NBATCH), 256, 0, stream>>>(vis, rnk, xe, dec_posp, xd, xdb);

  for (int i=0;i<2;i++)
    run_block(stream, xd, xdb, 5000, 2500, 40,
              wq[1][i], dqkv_b + i*2304, wo[1][i], dout_b + i*768,
              w1t[1][i], db1 + i*2048, w2t[1][i], db2 + i*768,
              dg1 + i*768, dbe1 + i*768, dg2 + i*768, dbe2 + i*768,
              qkvb, vt, aob, ffnb, tmp);

  gemm_kernel<1><<<dim3(40, 6), 256, 0, stream>>>(xdb, wfin, fout_b, nullptr,
                                                  (float*)d_out, 5000, 768, 768);
}

// Round 4
// 1021.794 us; speedup vs baseline: 1.1712x; 1.0766x over previous
//
#include <hip/hip_runtime.h>
#include <hip/hip_bf16.h>
#include <cstdint>
#include <cstddef>

// ============================================================================
// MAE ViT forward (B=2, enc N=1250 x2 layers, dec N=2500 x2 layers, D=768,
// H=8, HD=96, FF=2048). All big matmuls via bf16 MFMA (fp32 accum); LN,
// softmax, residuals in fp32.
// R4: swapped QK^T (lane-local q-row softmax), per-lane max/sum + 2 shfls,
// exp2-fma fold, b64 P-pack via cvt_pk, GEMM-style swizzled P buffer.
// ============================================================================

#define NBATCH  2
#define NPATCH  2500
#define NVIS    1250
#define DMODEL  768
#define NHEAD   8
#define HDIM    96
#define FFDIM   2048
#define NPADV   2560   // padded N for V^T buffer

typedef __attribute__((ext_vector_type(8))) short bf16x8;
typedef __attribute__((ext_vector_type(4))) float f32x4;

__device__ __forceinline__ short f2bf(float f){
  union { float f; unsigned u; } x; x.f = f;
  unsigned r = x.u + 0x7fffu + ((x.u >> 16) & 1u);   // RNE
  return (short)(r >> 16);
}

__device__ __forceinline__ void async_copy16(void* lds, const void* g){
  __builtin_amdgcn_global_load_lds(
      (const __attribute__((address_space(1))) unsigned int*)g,
      (__attribute__((address_space(3))) unsigned int*)lds, 16, 0, 0);
}

// ---------------------------------------------------------------------------
// Batched weight transpose + bf16 cast:  src (K,N) f32  ->  dst (N,K) bf16
// ---------------------------------------------------------------------------
struct TJob { const float* src; short* dst; int K; int N; int tile_base; int tiles_x; };
struct TJobs { TJob j[17]; };

__global__ __launch_bounds__(256) void transpose_all_kernel(TJobs jobs){
  int bid = blockIdx.x;
  int ji = 0;
  #pragma unroll
  for (int k=1;k<17;k++) if (bid >= jobs.j[k].tile_base) ji = k;
  TJob jb = jobs.j[ji];
  int lt = bid - jb.tile_base;
  int tx = lt % jb.tiles_x, ty = lt / jb.tiles_x;
  __shared__ float tile[32][33];
  int lx = threadIdx.x & 31, ly = threadIdx.x >> 5;
  #pragma unroll
  for (int r=0;r<4;r++)
    tile[ly + r*8][lx] = jb.src[(size_t)(ty*32 + ly + r*8)*jb.N + tx*32 + lx];
  __syncthreads();
  #pragma unroll
  for (int r=0;r<4;r++)
    jb.dst[(size_t)(tx*32 + ly + r*8)*jb.K + ty*32 + lx] = f2bf(tile[lx][ly + r*8]);
}

// ---------------------------------------------------------------------------
// GEMM: C(M,Nc) = A(M,K)bf16 @ Wt(Nc,K)bf16^T + bias.  MODE 0: bf16 out,
// 1: f32 out, 2: bf16 out + ReLU.  128x128 tile, BK=64, 4 waves,
// global_load_lds(16B) with XOR seg-swizzle (linear dest, pre-swizzled src).
// ---------------------------------------------------------------------------
template<int MODE>
__global__ __launch_bounds__(256) void gemm_kernel(const short* __restrict__ A,
    const short* __restrict__ Wt, const float* __restrict__ bias,
    short* __restrict__ Cb, float* __restrict__ Cf, int M, int Nc, int K){
  __shared__ short ldsA[128*64];
  __shared__ short ldsB[128*64];
  const int t = threadIdx.x, w = t>>6, ln = t&63;
  const int m0 = blockIdx.x*128, n0 = blockIdx.y*128;
  const int wr = (w>>1)*64, wc = (w&1)*64;
  const f32x4 fz = {0.f,0.f,0.f,0.f};
  f32x4 acc[4][4];
  #pragma unroll
  for (int mi=0;mi<4;mi++)
    #pragma unroll
    for (int ni=0;ni<4;ni++) acc[mi][ni] = fz;
  const int nkt = K >> 6;
  for (int kt=0; kt<nkt; kt++){
    #pragma unroll
    for (int c=0;c<4;c++){
      int chunk = c*256 + t;
      int row = chunk>>3, seg = chunk&7, sgs = seg ^ (row&7);
      int gm = m0 + row; if (gm >= M) gm = M-1;           // clamp; stores masked
      async_copy16((char*)ldsA + c*4096 + w*1024, A  + (size_t)gm*K      + kt*64 + sgs*8);
      async_copy16((char*)ldsB + c*4096 + w*1024, Wt + (size_t)(n0+row)*K + kt*64 + sgs*8);
    }
    __syncthreads();                                     // drains vmcnt
    #pragma unroll
    for (int ks=0;ks<2;ks++){
      bf16x8 af[4], bfr[4];
      #pragma unroll
      for (int mi=0;mi<4;mi++){
        int r = wr + mi*16 + (ln&15);
        int d = ks*4 + (ln>>4);
        af[mi]  = *(const bf16x8*)((const char*)ldsA + r*128 + ((d^(r&7))*16));
        int cc = wc + mi*16 + (ln&15);
        bfr[mi] = *(const bf16x8*)((const char*)ldsB + cc*128 + ((d^(cc&7))*16));
      }
      #pragma unroll
      for (int mi=0;mi<4;mi++)
        #pragma unroll
        for (int ni=0;ni<4;ni++)
          acc[mi][ni] = __builtin_amdgcn_mfma_f32_16x16x32_bf16(af[mi], bfr[ni], acc[mi][ni], 0,0,0);
    }
    __syncthreads();
  }
  float bv[4];
  #pragma unroll
  for (int ni=0;ni<4;ni++) bv[ni] = bias[n0 + wc + ni*16 + (ln&15)];
  #pragma unroll
  for (int mi=0;mi<4;mi++){
    #pragma unroll
    for (int j=0;j<4;j++){
      int gr = m0 + wr + mi*16 + (ln>>4)*4 + j;
      if (gr < M){
        #pragma unroll
        for (int ni=0;ni<4;ni++){
          float v = acc[mi][ni][j] + bv[ni];
          if (MODE==2) v = fmaxf(v, 0.f);
          int gc = n0 + wc + ni*16 + (ln&15);
          if (MODE==1) Cf[(size_t)gr*Nc + gc] = v;
          else         Cb[(size_t)gr*Nc + gc] = f2bf(v);
        }
      }
    }
  }
}

// ---------------------------------------------------------------------------
// V transpose: qkv(M,2304) v-part -> vt[b][h][hd][n] (row len NPADV), zero pad
// ---------------------------------------------------------------------------
__global__ __launch_bounds__(256) void vtrans_kernel(const short* __restrict__ qkv,
    short* __restrict__ vt, int N){
  int bh = blockIdx.z;
  int b = bh >> 3, h = bh & 7;
  int n0 = blockIdx.x*32, hd0 = blockIdx.y*32;
  __shared__ short tile[32][33];
  int lx = threadIdx.x & 31, ly = threadIdx.x >> 5;
  #pragma unroll
  for (int r=0;r<4;r++){
    int n = n0 + ly + r*8;
    short val = 0;
    if (n < N) val = qkv[(size_t)(b*N+n)*2304 + 1536 + h*96 + hd0 + lx];
    tile[ly+r*8][lx] = val;
  }
  __syncthreads();
  #pragma unroll
  for (int r=0;r<4;r++){
    int hd = hd0 + ly + r*8, n = n0 + lx;
    vt[(size_t)(bh*96 + hd)*NPADV + n] = tile[lx][ly+r*8];
  }
}

// ---------------------------------------------------------------------------
// Flash attention R4: 64 q-rows/block, 4 waves (16 q-rows each).
// Swapped QK^T: mfma(K,Q) -> lane holds P[q=col][kv=tt*16+hi*4+j] => softmax
// is lane-local (15 fmax/add + 2 shfl_xor).  P packed to b64, stored in
// GEMM-style XOR-swizzled per-wave [16][64] bf16 buffer, read back as b128
// A-frags for PV.  exp2-domain with fused scale; defer-max THR=11.5.
// ---------------------------------------------------------------------------
__global__ __launch_bounds__(256) void attn_kernel(const short* __restrict__ qkv,
    const short* __restrict__ vt, short* __restrict__ ao, int N, int NT){
  __shared__ short Ks[64*128];   // 64 rows x 16 segs x 8 shorts (swizzled; 12 real)
  __shared__ short Vs[96*64];    // 96 rows x  8 segs x 8 shorts (swizzled)
  __shared__ short Ps[4*1024];   // per-wave [16 q][64 kv] bf16, XOR-swizzled
  const int t = threadIdx.x, w = t>>6, ln = t&63;
  const int col = ln & 15, hi = ln >> 4;
  const int bh = blockIdx.y, b = bh >> 3, h = bh & 7;
  const int q0 = blockIdx.x * 64;
  short* Pw = &Ps[w*1024];
  const float scale2 = 0.14724974f;   // (1/sqrt(96)) * log2(e)

  // Q fragments straight from global (B-frag: col=q, k-slice (ks*4+hi)*8)
  bf16x8 qf[3];
  {
    int gq = q0 + w*16 + col; if (gq >= N) gq = N-1;
    const short* qrow = qkv + (size_t)(b*N+gq)*2304 + h*96;
    #pragma unroll
    for (int ks=0;ks<3;ks++)
      qf[ks] = *(const bf16x8*)(qrow + ks*32 + hi*8);
  }
  const f32x4 fz = {0.f,0.f,0.f,0.f};
  f32x4 o[6];
  #pragma unroll
  for (int g=0; g<6; g++) o[g] = fz;
  float mrun = -3e38f;   // scaled(log2) domain, for q-row = col
  float srun = 0.f;

  for (int kt=0; kt<NT; kt++){
    int n0 = kt*64;
    #pragma unroll
    for (int i=0;i<4;i++){         // stage K (16 segs; segs 12-15 dummy)
      int chunk = i*256 + t, row = chunk>>4, seg = chunk&15;
      int s2 = seg ^ (row&7);
      int gn = n0 + row; if (gn >= N) gn = N-1;
      const short* src = qkv + (size_t)(b*N+gn)*2304 + 768 + h*96
                       + ((s2 < 12) ? s2*8 : 0);
      async_copy16((char*)Ks + i*4096 + w*1024, src);
    }
    #pragma unroll
    for (int i=0;i<3;i++){         // stage V^T
      int chunk = i*256 + t, row = chunk>>3, seg = chunk&7;
      int s2 = seg ^ (row&7);
      const short* src = vt + (size_t)(bh*96 + row)*NPADV + n0 + s2*8;
      async_copy16((char*)Vs + i*4096 + w*1024, src);
    }
    __syncthreads();               // drains vmcnt

    // QK^T swapped: D[kv-within-16 = hi*4+j][q = col]
    f32x4 s[4];
    __builtin_amdgcn_s_setprio(1);
    #pragma unroll
    for (int tt=0;tt<4;tt++){
      f32x4 sc = fz;
      #pragma unroll
      for (int ks=0;ks<3;ks++){
        int r = tt*16 + col, d = ks*4 + hi;
        bf16x8 kb = *(const bf16x8*)((const char*)Ks + r*256 + ((d ^ (r&7))*16));
        sc = __builtin_amdgcn_mfma_f32_16x16x32_bf16(kb, qf[ks], sc, 0,0,0);
      }
      s[tt] = sc;
    }
    __builtin_amdgcn_s_setprio(0);

    if (n0 + 64 > N){              // tail-tile kv mask (per-lane kv index)
      #pragma unroll
      for (int tt=0;tt<4;tt++)
        #pragma unroll
        for (int j=0;j<4;j++)
          if (n0 + tt*16 + hi*4 + j >= N) s[tt][j] = -3e38f;
    }
    // lane-local row max over 16 raw scores + cross-hi reduce (2 shfls)
    float mraw = s[0][0];
    #pragma unroll
    for (int tt=0;tt<4;tt++)
      #pragma unroll
      for (int j=0;j<4;j++) if (tt|j) mraw = fmaxf(mraw, s[tt][j]);
    mraw = fmaxf(mraw, __shfl_xor(mraw, 16));
    mraw = fmaxf(mraw, __shfl_xor(mraw, 32));
    float mxs = mraw * scale2;
    if (__any(mxs > mrun + 11.5f)){   // defer-max: rescale only on growth
      float mnew = fmaxf(mrun, mxs);
      float alpha = exp2f(mrun - mnew);
      mrun = mnew; srun *= alpha;
      float a0 = __shfl(alpha, hi*4+0), a1 = __shfl(alpha, hi*4+1);
      float a2 = __shfl(alpha, hi*4+2), a3 = __shfl(alpha, hi*4+3);
      #pragma unroll
      for (int g=0; g<6; g++){
        o[g][0] *= a0; o[g][1] *= a1; o[g][2] *= a2; o[g][3] *= a3;
      }
    }
    // exp2(fma) + per-lane sum + pack 4 bf16 -> b64 swizzled store
    float psum = 0.f;
    #pragma unroll
    for (int tt=0;tt<4;tt++){
      float p0 = exp2f(fmaf(s[tt][0], scale2, -mrun));
      float p1 = exp2f(fmaf(s[tt][1], scale2, -mrun));
      float p2 = exp2f(fmaf(s[tt][2], scale2, -mrun));
      float p3 = exp2f(fmaf(s[tt][3], scale2, -mrun));
      psum += (p0+p1) + (p2+p3);
      __hip_bfloat162 lo = __float22bfloat162_rn(float2{p0,p1});
      __hip_bfloat162 hn = __float22bfloat162_rn(float2{p2,p3});
      uint2 pk; pk.x = *reinterpret_cast<unsigned*>(&lo);
      pk.y = *reinterpret_cast<unsigned*>(&hn);
      char* wp = (char*)Pw + col*128 + (((2*tt + (hi>>1)) ^ (col&7))<<4) + ((hi&1)<<3);
      *reinterpret_cast<uint2*>(wp) = pk;
    }
    srun += psum;
    // PV: A = P (row=q=col, k=kv), B = V^T
    __builtin_amdgcn_s_setprio(1);
    #pragma unroll
    for (int ks2=0; ks2<2; ks2++){
      bf16x8 pa = *(const bf16x8*)((const char*)Pw + col*128
                    + (((ks2*4 + hi) ^ (col&7))<<4));
      #pragma unroll
      for (int g=0; g<6; g++){
        int r = g*16 + col, d = ks2*4 + hi;
        bf16x8 vb = *(const bf16x8*)((const char*)Vs + r*128 + ((d ^ (r&7))*16));
        o[g] = __builtin_amdgcn_mfma_f32_16x16x32_bf16(pa, vb, o[g], 0,0,0);
      }
    }
    __builtin_amdgcn_s_setprio(0);
    __syncthreads();
  }
  // final l reduce (cross-hi) + redistribute to C rows
  srun += __shfl_xor(srun, 16);
  srun += __shfl_xor(srun, 32);
  float inv = 1.f / srun;
  float i0 = __shfl(inv, hi*4+0), i1 = __shfl(inv, hi*4+1);
  float i2 = __shfl(inv, hi*4+2), i3 = __shfl(inv, hi*4+3);
  #pragma unroll
  for (int g=0; g<6; g++){
    float ov[4] = {o[g][0]*i0, o[g][1]*i1, o[g][2]*i2, o[g][3]*i3};
    #pragma unroll
    for (int j=0;j<4;j++){
      int qr = q0 + w*16 + hi*4 + j;
      if (qr < N)
        ao[(size_t)(b*N+qr)*768 + h*96 + g*16 + col] = f2bf(ov[j]);
    }
  }
}

// ---------------------------------------------------------------------------
// LayerNorm(x + add) -> f32 + bf16.  One block per row (768), 256 threads.
// ---------------------------------------------------------------------------
__global__ __launch_bounds__(256) void ln_kernel(const float* __restrict__ xin,
    const float* __restrict__ add, const float* __restrict__ g,
    const float* __restrict__ be, float* __restrict__ xo, short* __restrict__ xob){
  int row = blockIdx.x, t = threadIdx.x;
  float e[3]; float s = 0.f;
  #pragma unroll
  for (int k=0;k<3;k++){
    size_t off = (size_t)row*768 + t + k*256;
    e[k] = xin[off] + add[off]; s += e[k];
  }
  #pragma unroll
  for (int d=32; d; d>>=1) s += __shfl_xor(s, d);
  __shared__ float red[8];
  if ((t&63)==0) red[t>>6] = s;
  __syncthreads();
  float mean = (red[0]+red[1]+red[2]+red[3]) * (1.f/768.f);
  float vs = 0.f;
  #pragma unroll
  for (int k=0;k<3;k++){ float dd = e[k]-mean; vs += dd*dd; }
  #pragma unroll
  for (int d=32; d; d>>=1) vs += __shfl_xor(vs, d);
  if ((t&63)==0) red[4 + (t>>6)] = vs;
  __syncthreads();
  float rstd = rsqrtf((red[4]+red[5]+red[6]+red[7]) * (1.f/768.f) + 1e-5f);
  #pragma unroll
  for (int k=0;k<3;k++){
    int c = t + k*256;
    size_t off = (size_t)row*768 + c;
    float ov = (e[k]-mean)*rstd*g[c] + be[c];
    xo[off] = ov; xob[off] = f2bf(ov);
  }
}

// ---------------------------------------------------------------------------
// patchify + gather visible + enc_pos
// ---------------------------------------------------------------------------
__global__ __launch_bounds__(256) void patchify_kernel(const float* __restrict__ x,
    const int* __restrict__ vis, const float* __restrict__ enc_pos,
    float* __restrict__ xe, short* __restrict__ xeb){
  int b = blockIdx.y, i = blockIdx.x;
  int pidx = vis[b*NVIS + i];
  int gy = pidx / 50, gx = pidx - gy*50;
  #pragma unroll
  for (int k=0;k<3;k++){
    int d = threadIdx.x + k*256;
    int c = d >> 8, rr = d & 255, py = rr >> 4, px = rr & 15;
    float v = x[(((size_t)b*3 + c)*800 + gy*16 + py)*800 + gx*16 + px]
            + enc_pos[(size_t)i*768 + d];
    size_t off = (size_t)(b*NVIS + i)*768 + d;
    xe[off] = v; xeb[off] = f2bf(v);
  }
}

// rank(p) = #{j : vis[j] < p}  (reproduces full.at[b, sort(vis)].set(h))
__global__ __launch_bounds__(256) void rank_kernel(const int* __restrict__ vis,
    int* __restrict__ rnk){
  int b = blockIdx.y; int i = blockIdx.x*256 + threadIdx.x;
  if (i >= NVIS) return;
  int p = vis[b*NVIS + i]; int c = 0;
  for (int j=0;j<NVIS;j++) c += (vis[b*NVIS + j] < p) ? 1 : 0;
  rnk[b*NVIS + i] = c;
}

__global__ __launch_bounds__(256) void dec_init_kernel(const float* __restrict__ mask_token,
    const float* __restrict__ dec_pos, float* __restrict__ xd, short* __restrict__ xdb){
  int row = blockIdx.x;                 // b*2500 + p
  int p = row % NPATCH;
  #pragma unroll
  for (int k=0;k<3;k++){
    int c = threadIdx.x + k*256;
    float v = mask_token[c] + dec_pos[(size_t)p*768 + c];
    size_t off = (size_t)row*768 + c;
    xd[off] = v; xdb[off] = f2bf(v);
  }
}

__global__ __launch_bounds__(256) void scatter_kernel(const int* __restrict__ vis,
    const int* __restrict__ rnk, const float* __restrict__ xe,
    const float* __restrict__ dec_pos, float* __restrict__ xd, short* __restrict__ xdb){
  int b = blockIdx.y, i = blockIdx.x;
  int p = vis[b*NVIS+i]; int r = rnk[b*NVIS+i];
  #pragma unroll
  for (int k=0;k<3;k++){
    int c = threadIdx.x + k*256;
    float v = xe[(size_t)(b*NVIS + r)*768 + c] + dec_pos[(size_t)p*768 + c];
    size_t off = (size_t)(b*NPATCH + p)*768 + c;
    xd[off] = v; xdb[off] = f2bf(v);
  }
}

// ---------------------------------------------------------------------------
// host side
// ---------------------------------------------------------------------------
static void run_block(hipStream_t stream, float* xf, short* xb, int M, int N, int NT,
                      const short* wqkvT, const float* qkv_b, const short* woutT,
                      const float* out_b, const short* w1T, const float* b1,
                      const short* w2T, const float* b2,
                      const float* g1, const float* be1, const float* g2, const float* be2,
                      short* qkvb, short* vt, short* aob, short* ffnb, float* tmp){
  int mt = (M + 127)/128;
  gemm_kernel<0><<<dim3(mt, 18), 256, 0, stream>>>(xb, wqkvT, qkv_b, qkvb, nullptr, M, 2304, 768);
  vtrans_kernel<<<dim3(NT*2, 3, 16), 256, 0, stream>>>(qkvb, vt, N);
  attn_kernel<<<dim3(NT, 16), 256, 0, stream>>>(qkvb, vt, aob, N, NT);
  gemm_kernel<1><<<dim3(mt, 6), 256, 0, stream>>>(aob, woutT, out_b, nullptr, tmp, M, 768, 768);
  ln_kernel<<<M, 256, 0, stream>>>(xf, tmp, g1, be1, xf, xb);
  gemm_kernel<2><<<dim3(mt, 16), 256, 0, stream>>>(xb, w1T, b1, ffnb, nullptr, M, 2048, 768);
  gemm_kernel<1><<<dim3(mt, 6), 256, 0, stream>>>(ffnb, w2T, b2, nullptr, tmp, M, 768, 2048);
  ln_kernel<<<M, 256, 0, stream>>>(xf, tmp, g2, be2, xf, xb);
}

extern "C" void kernel_launch(void* const* d_in, const int* in_sizes, int n_in,
                              void* d_out, int out_size, void* d_ws, size_t ws_size,
                              hipStream_t stream){
  const float* x        = (const float*)d_in[0];
  const int*   vis      = (const int*)d_in[1];
  const float* eqkv_w   = (const float*)d_in[3];
  const float* eqkv_b   = (const float*)d_in[4];
  const float* eout_w   = (const float*)d_in[5];
  const float* eout_b   = (const float*)d_in[6];
  const float* ew1      = (const float*)d_in[7];
  const float* eb1      = (const float*)d_in[8];
  const float* ew2      = (const float*)d_in[9];
  const float* eb2      = (const float*)d_in[10];
  const float* eg1      = (const float*)d_in[11];
  const float* ebe1     = (const float*)d_in[12];
  const float* eg2      = (const float*)d_in[13];
  const float* ebe2     = (const float*)d_in[14];
  const float* dqkv_w   = (const float*)d_in[15];
  const float* dqkv_b   = (const float*)d_in[16];
  const float* dout_w   = (const float*)d_in[17];
  const float* dout_b   = (const float*)d_in[18];
  const float* dw1      = (const float*)d_in[19];
  const float* db1      = (const float*)d_in[20];
  const float* dw2      = (const float*)d_in[21];
  const float* db2      = (const float*)d_in[22];
  const float* dg1      = (const float*)d_in[23];
  const float* dbe1     = (const float*)d_in[24];
  const float* dg2      = (const float*)d_in[25];
  const float* dbe2     = (const float*)d_in[26];
  const float* fout_w   = (const float*)d_in[27];
  const float* fout_b   = (const float*)d_in[28];
  const float* mask_tok = (const float*)d_in[29];
  const float* enc_posp = (const float*)d_in[30];
  const float* dec_posp = (const float*)d_in[31];

  char* p = (char*)d_ws;
  auto alloc = [&](size_t bytes)->char*{ char* r = p; p += (bytes + 255) & ~(size_t)255; return r; };

  const float* qkvw_s[2] = {eqkv_w, dqkv_w};
  const float* outw_s[2] = {eout_w, dout_w};
  const float* w1_s[2]   = {ew1, dw1};
  const float* w2_s[2]   = {ew2, dw2};

  short *wq[2][2], *wo[2][2], *w1t[2][2], *w2t[2][2];
  TJobs jobs; int jidx = 0; int tbase = 0;
  auto addJob = [&](const float* src, short* dst, int K, int N){
    jobs.j[jidx].src = src; jobs.j[jidx].dst = dst; jobs.j[jidx].K = K; jobs.j[jidx].N = N;
    jobs.j[jidx].tile_base = tbase; jobs.j[jidx].tiles_x = N/32;
    tbase += (K/32)*(N/32); jidx++;
  };
  for (int s=0;s<2;s++)
    for (int i=0;i<2;i++){
      wq[s][i]  = (short*)alloc((size_t)2304*768*2);
      addJob(qkvw_s[s] + (size_t)i*768*2304, wq[s][i], 768, 2304);
      wo[s][i]  = (short*)alloc((size_t)768*768*2);
      addJob(outw_s[s] + (size_t)i*768*768, wo[s][i], 768, 768);
      w1t[s][i] = (short*)alloc((size_t)2048*768*2);
      addJob(w1_s[s] + (size_t)i*768*2048, w1t[s][i], 768, 2048);
      w2t[s][i] = (short*)alloc((size_t)768*2048*2);
      addJob(w2_s[s] + (size_t)i*2048*768, w2t[s][i], 2048, 768);
    }
  short* wfin = (short*)alloc((size_t)768*768*2);
  addJob(fout_w, wfin, 768, 768);
  int total_tiles = tbase;   // 22080

  float* xe   = (float*)alloc((size_t)2500*768*4);
  short* xeb  = (short*)alloc((size_t)2500*768*2);
  float* xd   = (float*)alloc((size_t)5000*768*4);
  short* xdb  = (short*)alloc((size_t)5000*768*2);
  short* qkvb = (short*)alloc((size_t)5000*2304*2);
  short* vt   = (short*)alloc((size_t)16*96*NPADV*2);
  short* aob  = (short*)alloc((size_t)5000*768*2);
  short* ffnb = (short*)alloc((size_t)5000*2048*2);
  float* tmp  = (float*)alloc((size_t)5000*768*4);
  int*   rnk  = (int*)alloc((size_t)2*NVIS*4);

  transpose_all_kernel<<<total_tiles, 256, 0, stream>>>(jobs);
  patchify_kernel<<<dim3(NVIS, NBATCH), 256, 0, stream>>>(x, vis, enc_posp, xe, xeb);
  rank_kernel<<<dim3((NVIS+255)/256, NBATCH), 256, 0, stream>>>(vis, rnk);

  for (int i=0;i<2;i++)
    run_block(stream, xe, xeb, 2500, 1250, 20,
              wq[0][i], eqkv_b + i*2304, wo[0][i], eout_b + i*768,
              w1t[0][i], eb1 + i*2048, w2t[0][i], eb2 + i*768,
              eg1 + i*768, ebe1 + i*768, eg2 + i*768, ebe2 + i*768,
              qkvb, vt, aob, ffnb, tmp);

  dec_init_kernel<<<NBATCH*NPATCH, 256, 0, stream>>>(mask_tok, dec_posp, xd, xdb);
  scatter_kernel<<<dim3(NVIS, NBATCH), 256, 0, stream>>>(vis, rnk, xe, dec_posp, xd, xdb);

  for (int i=0;i<2;i++)
    run_block(stream, xd, xdb, 5000, 2500, 40,
              wq[1][i], dqkv_b + i*2304, wo[1][i], dout_b + i*768,
              w1t[1][i], db1 + i*2048, w2t[1][i], db2 + i*768,
              dg1 + i*768, dbe1 + i*768, dg2 + i*768, dbe2 + i*768,
              qkvb, vt, aob, ffnb, tmp);

  gemm_kernel<1><<<dim3(40, 6), 256, 0, stream>>>(xdb, wfin, fout_b, nullptr,
                                                  (float*)d_out, 5000, 768, 768);
}

// Round 6
// 996.246 us; speedup vs baseline: 1.2012x; 1.0256x over previous
//
#include <hip/hip_runtime.h>
#include <hip/hip_bf16.h>
#include <cstdint>
#include <cstddef>

// ============================================================================
// MAE ViT forward (B=2, enc N=1250 x2 layers, dec N=2500 x2 layers, D=768,
// H=8, HD=96, FF=2048). All big matmuls via bf16 MFMA (fp32 accum); LN,
// softmax, residuals in fp32.
// R6: fix R5 kv-split partial-buffer routing (half = NS/2 in producer AND
// merge; dec split-1 previously overflowed tmp and clobbered pm/pl).
// ============================================================================

#define NBATCH  2
#define NPATCH  2500
#define NVIS    1250
#define DMODEL  768
#define NHEAD   8
#define HDIM    96
#define FFDIM   2048
#define NPADV   2560   // padded N for V^T buffer

typedef __attribute__((ext_vector_type(8))) short bf16x8;
typedef __attribute__((ext_vector_type(4))) float f32x4;

__device__ __forceinline__ short f2bf(float f){
  union { float f; unsigned u; } x; x.f = f;
  unsigned r = x.u + 0x7fffu + ((x.u >> 16) & 1u);   // RNE
  return (short)(r >> 16);
}

__device__ __forceinline__ void async_copy16(void* lds, const void* g){
  __builtin_amdgcn_global_load_lds(
      (const __attribute__((address_space(1))) unsigned int*)g,
      (__attribute__((address_space(3))) unsigned int*)lds, 16, 0, 0);
}

// ---------------------------------------------------------------------------
// Batched weight transpose + bf16 cast:  src (K,N) f32  ->  dst (N,K) bf16
// ---------------------------------------------------------------------------
struct TJob { const float* src; short* dst; int K; int N; int tile_base; int tiles_x; };
struct TJobs { TJob j[17]; };

__global__ __launch_bounds__(256) void transpose_all_kernel(TJobs jobs){
  int bid = blockIdx.x;
  int ji = 0;
  #pragma unroll
  for (int k=1;k<17;k++) if (bid >= jobs.j[k].tile_base) ji = k;
  TJob jb = jobs.j[ji];
  int lt = bid - jb.tile_base;
  int tx = lt % jb.tiles_x, ty = lt / jb.tiles_x;
  __shared__ float tile[32][33];
  int lx = threadIdx.x & 31, ly = threadIdx.x >> 5;
  #pragma unroll
  for (int r=0;r<4;r++)
    tile[ly + r*8][lx] = jb.src[(size_t)(ty*32 + ly + r*8)*jb.N + tx*32 + lx];
  __syncthreads();
  #pragma unroll
  for (int r=0;r<4;r++)
    jb.dst[(size_t)(tx*32 + ly + r*8)*jb.K + ty*32 + lx] = f2bf(tile[lx][ly + r*8]);
}

// ---------------------------------------------------------------------------
// GEMM: C(M,Nc) = A(M,K)bf16 @ Wt(Nc,K)bf16^T + bias.  MODE 0: bf16 out,
// 1: f32 out (split-K via blockIdx.z -> Cf0/Cf1), 2: bf16 out + ReLU.
// 128x128 tile, BK=64, 4 waves, global_load_lds(16B) w/ XOR seg-swizzle.
// ---------------------------------------------------------------------------
template<int MODE>
__global__ __launch_bounds__(256) void gemm_kernel(const short* __restrict__ A,
    const short* __restrict__ Wt, const float* __restrict__ bias,
    short* __restrict__ Cb, float* __restrict__ Cf0, float* __restrict__ Cf1,
    int M, int Nc, int K, int nkt_per){
  __shared__ short ldsA[128*64];
  __shared__ short ldsB[128*64];
  const int t = threadIdx.x, w = t>>6, ln = t&63;
  const int m0 = blockIdx.x*128, n0 = blockIdx.y*128;
  const int z = blockIdx.z;
  const int wr = (w>>1)*64, wc = (w&1)*64;
  const f32x4 fz = {0.f,0.f,0.f,0.f};
  f32x4 acc[4][4];
  #pragma unroll
  for (int mi=0;mi<4;mi++)
    #pragma unroll
    for (int ni=0;ni<4;ni++) acc[mi][ni] = fz;
  const int ktb = z*nkt_per;
  for (int kk=0; kk<nkt_per; kk++){
    int kt = ktb + kk;
    #pragma unroll
    for (int c=0;c<4;c++){
      int chunk = c*256 + t;
      int row = chunk>>3, seg = chunk&7, sgs = seg ^ (row&7);
      int gm = m0 + row; if (gm >= M) gm = M-1;           // clamp; stores masked
      async_copy16((char*)ldsA + c*4096 + w*1024, A  + (size_t)gm*K      + kt*64 + sgs*8);
      async_copy16((char*)ldsB + c*4096 + w*1024, Wt + (size_t)(n0+row)*K + kt*64 + sgs*8);
    }
    __syncthreads();                                     // drains vmcnt
    #pragma unroll
    for (int ks=0;ks<2;ks++){
      bf16x8 af[4], bfr[4];
      #pragma unroll
      for (int mi=0;mi<4;mi++){
        int r = wr + mi*16 + (ln&15);
        int d = ks*4 + (ln>>4);
        af[mi]  = *(const bf16x8*)((const char*)ldsA + r*128 + ((d^(r&7))*16));
        int cc = wc + mi*16 + (ln&15);
        bfr[mi] = *(const bf16x8*)((const char*)ldsB + cc*128 + ((d^(cc&7))*16));
      }
      #pragma unroll
      for (int mi=0;mi<4;mi++)
        #pragma unroll
        for (int ni=0;ni<4;ni++)
          acc[mi][ni] = __builtin_amdgcn_mfma_f32_16x16x32_bf16(af[mi], bfr[ni], acc[mi][ni], 0,0,0);
    }
    __syncthreads();
  }
  float bv[4];
  #pragma unroll
  for (int ni=0;ni<4;ni++)
    bv[ni] = (z==0) ? bias[n0 + wc + ni*16 + (ln&15)] : 0.f;
  float* Cf = (z==0) ? Cf0 : Cf1;
  #pragma unroll
  for (int mi=0;mi<4;mi++){
    #pragma unroll
    for (int j=0;j<4;j++){
      int gr = m0 + wr + mi*16 + (ln>>4)*4 + j;
      if (gr < M){
        #pragma unroll
        for (int ni=0;ni<4;ni++){
          float v = acc[mi][ni][j] + bv[ni];
          if (MODE==2) v = fmaxf(v, 0.f);
          int gc = n0 + wc + ni*16 + (ln&15);
          if (MODE==1) Cf[(size_t)gr*Nc + gc] = v;
          else         Cb[(size_t)gr*Nc + gc] = f2bf(v);
        }
      }
    }
  }
}

// ---------------------------------------------------------------------------
// V transpose: qkv(M,2304) v-part -> vt[b][h][hd][n] (row len NPADV), zero pad
// ---------------------------------------------------------------------------
__global__ __launch_bounds__(256) void vtrans_kernel(const short* __restrict__ qkv,
    short* __restrict__ vt, int N){
  int bh = blockIdx.z;
  int b = bh >> 3, h = bh & 7;
  int n0 = blockIdx.x*32, hd0 = blockIdx.y*32;
  __shared__ short tile[32][33];
  int lx = threadIdx.x & 31, ly = threadIdx.x >> 5;
  #pragma unroll
  for (int r=0;r<4;r++){
    int n = n0 + ly + r*8;
    short val = 0;
    if (n < N) val = qkv[(size_t)(b*N+n)*2304 + 1536 + h*96 + hd0 + lx];
    tile[ly+r*8][lx] = val;
  }
  __syncthreads();
  #pragma unroll
  for (int r=0;r<4;r++){
    int hd = hd0 + ly + r*8, n = n0 + lx;
    vt[(size_t)(bh*96 + hd)*NPADV + n] = tile[lx][ly+r*8];
  }
}

// ---------------------------------------------------------------------------
// Flash attention R6: 64 q-rows/block, 4 waves; kv range split across
// blockIdx.z (flash-decode).  Swapped QK^T (lane-local q-row softmax),
// exp2-domain fused scale, defer-max, b64 P pack into swizzled LDS.
// Partial outputs: unnormalized O (f32) + per-row m,l; merged by
// attn_merge_kernel.  Split s goes to poA if s<half else poB (capacity!).
// ---------------------------------------------------------------------------
__global__ __launch_bounds__(256) void attn_kernel(const short* __restrict__ qkv,
    const short* __restrict__ vt, float* __restrict__ poA, float* __restrict__ poB,
    float* __restrict__ pm, float* __restrict__ pl, int N, int NT, int TPS, int half){
  __shared__ short Ks[64*128];   // 64 rows x 16 segs x 8 shorts (swizzled; 12 real)
  __shared__ short Vs[96*64];    // 96 rows x  8 segs x 8 shorts (swizzled)
  __shared__ short Ps[4*1024];   // per-wave [16 q][64 kv] bf16, XOR-swizzled
  const int t = threadIdx.x, w = t>>6, ln = t&63;
  const int col = ln & 15, hi = ln >> 4;
  const int bh = blockIdx.y, b = bh >> 3, h = bh & 7;
  const int q0 = blockIdx.x * 64;
  const int z = blockIdx.z;
  const int kt0 = z*TPS, kt1 = (kt0 + TPS < NT) ? kt0 + TPS : NT;
  short* Pw = &Ps[w*1024];
  const float scale2 = 0.14724974f;   // (1/sqrt(96)) * log2(e)

  bf16x8 qf[3];
  {
    int gq = q0 + w*16 + col; if (gq >= N) gq = N-1;
    const short* qrow = qkv + (size_t)(b*N+gq)*2304 + h*96;
    #pragma unroll
    for (int ks=0;ks<3;ks++)
      qf[ks] = *(const bf16x8*)(qrow + ks*32 + hi*8);
  }
  const f32x4 fz = {0.f,0.f,0.f,0.f};
  f32x4 o[6];
  #pragma unroll
  for (int g=0; g<6; g++) o[g] = fz;
  float mrun = -3e38f;   // scaled(log2) domain, for q-row = col
  float srun = 0.f;

  for (int kt=kt0; kt<kt1; kt++){
    int n0 = kt*64;
    #pragma unroll
    for (int i=0;i<4;i++){         // stage K (16 segs; segs 12-15 dummy)
      int chunk = i*256 + t, row = chunk>>4, seg = chunk&15;
      int s2 = seg ^ (row&7);
      int gn = n0 + row; if (gn >= N) gn = N-1;
      const short* src = qkv + (size_t)(b*N+gn)*2304 + 768 + h*96
                       + ((s2 < 12) ? s2*8 : 0);
      async_copy16((char*)Ks + i*4096 + w*1024, src);
    }
    #pragma unroll
    for (int i=0;i<3;i++){         // stage V^T
      int chunk = i*256 + t, row = chunk>>3, seg = chunk&7;
      int s2 = seg ^ (row&7);
      const short* src = vt + (size_t)(bh*96 + row)*NPADV + n0 + s2*8;
      async_copy16((char*)Vs + i*4096 + w*1024, src);
    }
    __syncthreads();               // drains vmcnt

    // QK^T swapped: D[kv-within-16 = hi*4+j][q = col]
    f32x4 s[4];
    __builtin_amdgcn_s_setprio(1);
    #pragma unroll
    for (int tt=0;tt<4;tt++){
      f32x4 sc = fz;
      #pragma unroll
      for (int ks=0;ks<3;ks++){
        int r = tt*16 + col, d = ks*4 + hi;
        bf16x8 kb = *(const bf16x8*)((const char*)Ks + r*256 + ((d ^ (r&7))*16));
        sc = __builtin_amdgcn_mfma_f32_16x16x32_bf16(kb, qf[ks], sc, 0,0,0);
      }
      s[tt] = sc;
    }
    __builtin_amdgcn_s_setprio(0);

    if (n0 + 64 > N){              // tail-tile kv mask (per-lane kv index)
      #pragma unroll
      for (int tt=0;tt<4;tt++)
        #pragma unroll
        for (int j=0;j<4;j++)
          if (n0 + tt*16 + hi*4 + j >= N) s[tt][j] = -3e38f;
    }
    // lane-local row max over 16 raw scores + cross-hi reduce (2 shfls)
    float mraw = s[0][0];
    #pragma unroll
    for (int tt=0;tt<4;tt++)
      #pragma unroll
      for (int j=0;j<4;j++) if (tt|j) mraw = fmaxf(mraw, s[tt][j]);
    mraw = fmaxf(mraw, __shfl_xor(mraw, 16));
    mraw = fmaxf(mraw, __shfl_xor(mraw, 32));
    float mxs = mraw * scale2;
    if (__any(mxs > mrun + 11.5f)){   // defer-max: rescale only on growth
      float mnew = fmaxf(mrun, mxs);
      float alpha = exp2f(mrun - mnew);
      mrun = mnew; srun *= alpha;
      float a0 = __shfl(alpha, hi*4+0), a1 = __shfl(alpha, hi*4+1);
      float a2 = __shfl(alpha, hi*4+2), a3 = __shfl(alpha, hi*4+3);
      #pragma unroll
      for (int g=0; g<6; g++){
        o[g][0] *= a0; o[g][1] *= a1; o[g][2] *= a2; o[g][3] *= a3;
      }
    }
    // exp2(fma) + per-lane sum + pack 4 bf16 -> b64 swizzled store
    float psum = 0.f;
    #pragma unroll
    for (int tt=0;tt<4;tt++){
      float p0 = exp2f(fmaf(s[tt][0], scale2, -mrun));
      float p1 = exp2f(fmaf(s[tt][1], scale2, -mrun));
      float p2 = exp2f(fmaf(s[tt][2], scale2, -mrun));
      float p3 = exp2f(fmaf(s[tt][3], scale2, -mrun));
      psum += (p0+p1) + (p2+p3);
      __hip_bfloat162 lo = __float22bfloat162_rn(float2{p0,p1});
      __hip_bfloat162 hn = __float22bfloat162_rn(float2{p2,p3});
      uint2 pk; pk.x = *reinterpret_cast<unsigned*>(&lo);
      pk.y = *reinterpret_cast<unsigned*>(&hn);
      char* wp = (char*)Pw + col*128 + (((2*tt + (hi>>1)) ^ (col&7))<<4) + ((hi&1)<<3);
      *reinterpret_cast<uint2*>(wp) = pk;
    }
    srun += psum;
    // PV: A = P (row=q=col, k=kv), B = V^T
    __builtin_amdgcn_s_setprio(1);
    #pragma unroll
    for (int ks2=0; ks2<2; ks2++){
      bf16x8 pa = *(const bf16x8*)((const char*)Pw + col*128
                    + (((ks2*4 + hi) ^ (col&7))<<4));
      #pragma unroll
      for (int g=0; g<6; g++){
        int r = g*16 + col, d = ks2*4 + hi;
        bf16x8 vb = *(const bf16x8*)((const char*)Vs + r*128 + ((d ^ (r&7))*16));
        o[g] = __builtin_amdgcn_mfma_f32_16x16x32_bf16(pa, vb, o[g], 0,0,0);
      }
    }
    __builtin_amdgcn_s_setprio(0);
    __syncthreads();
  }
  // partial epilogue: l reduce (cross-hi), write m/l per q-row + raw O
  srun += __shfl_xor(srun, 16);
  srun += __shfl_xor(srun, 32);
  int qrow = q0 + w*16 + col;
  if (hi == 0 && qrow < N){
    size_t mi = ((size_t)(z*2 + b)*8 + h)*2560 + qrow;
    pm[mi] = mrun; pl[mi] = srun;
  }
  size_t spl = (size_t)2*N*768;
  float* po = (z < half) ? (poA + (size_t)z*spl)
                         : (poB + (size_t)(z-half)*spl);
  #pragma unroll
  for (int g=0; g<6; g++)
    #pragma unroll
    for (int j=0;j<4;j++){
      int qr = q0 + w*16 + hi*4 + j;
      if (qr < N)
        po[(size_t)(b*N+qr)*768 + h*96 + g*16 + col] = o[g][j];
    }
}

// ---------------------------------------------------------------------------
// Merge NS kv-split partials: o = sum_s(po_s * 2^(m_s-m)) / sum_s(l_s*2^(m_s-m))
// ---------------------------------------------------------------------------
__global__ __launch_bounds__(256) void attn_merge_kernel(const float* __restrict__ poA,
    const float* __restrict__ poB, const float* __restrict__ pm,
    const float* __restrict__ pl, short* __restrict__ ao, int N, int NS){
  int x = blockIdx.x; int b = x / N, qr = x - b*N;
  int t = threadIdx.x;
  int half = NS >> 1;
  size_t rowoff = (size_t)(b*N+qr)*768;
  size_t spl = (size_t)2*N*768;
  #pragma unroll
  for (int k=0;k<3;k++){
    int c = t + k*256;
    int h = c/96;
    size_t mi0 = ((size_t)b*8 + h)*2560 + qr;
    float m = -3e38f;
    for (int s=0;s<NS;s++)
      m = fmaxf(m, pm[(size_t)s*(2*8*2560) + mi0]);
    float num = 0.f, den = 0.f;
    for (int s=0;s<NS;s++){
      size_t base = (size_t)s*(2*8*2560) + mi0;
      float wgt = exp2f(pm[base] - m);
      den += pl[base]*wgt;
      const float* po = (s < half) ? poA + (size_t)s*spl
                                   : poB + (size_t)(s-half)*spl;
      num += po[rowoff + c]*wgt;
    }
    ao[rowoff + c] = f2bf(num/den);
  }
}

// ---------------------------------------------------------------------------
// LayerNorm(x + add0 + add1) -> f32 + bf16.  One block per row, 256 threads.
// ---------------------------------------------------------------------------
__global__ __launch_bounds__(256) void ln_kernel(const float* __restrict__ xin,
    const float* __restrict__ add0, const float* __restrict__ add1,
    const float* __restrict__ g, const float* __restrict__ be,
    float* __restrict__ xo, short* __restrict__ xob){
  int row = blockIdx.x, t = threadIdx.x;
  float e[3]; float s = 0.f;
  #pragma unroll
  for (int k=0;k<3;k++){
    size_t off = (size_t)row*768 + t + k*256;
    e[k] = xin[off] + add0[off] + add1[off]; s += e[k];
  }
  #pragma unroll
  for (int d=32; d; d>>=1) s += __shfl_xor(s, d);
  __shared__ float red[8];
  if ((t&63)==0) red[t>>6] = s;
  __syncthreads();
  float mean = (red[0]+red[1]+red[2]+red[3]) * (1.f/768.f);
  float vs = 0.f;
  #pragma unroll
  for (int k=0;k<3;k++){ float dd = e[k]-mean; vs += dd*dd; }
  #pragma unroll
  for (int d=32; d; d>>=1) vs += __shfl_xor(vs, d);
  if ((t&63)==0) red[4 + (t>>6)] = vs;
  __syncthreads();
  float rstd = rsqrtf((red[4]+red[5]+red[6]+red[7]) * (1.f/768.f) + 1e-5f);
  #pragma unroll
  for (int k=0;k<3;k++){
    int c = t + k*256;
    size_t off = (size_t)row*768 + c;
    float ov = (e[k]-mean)*rstd*g[c] + be[c];
    xo[off] = ov; xob[off] = f2bf(ov);
  }
}

// out = a + b (final split-K merge), f32, grid-stride
__global__ __launch_bounds__(256) void add2_kernel(const float* __restrict__ a,
    const float* __restrict__ b, float* __restrict__ out, int n){
  for (int i = blockIdx.x*256 + threadIdx.x; i < n; i += gridDim.x*256)
    out[i] = a[i] + b[i];
}

// ---------------------------------------------------------------------------
// patchify + gather visible + enc_pos
// ---------------------------------------------------------------------------
__global__ __launch_bounds__(256) void patchify_kernel(const float* __restrict__ x,
    const int* __restrict__ vis, const float* __restrict__ enc_pos,
    float* __restrict__ xe, short* __restrict__ xeb){
  int b = blockIdx.y, i = blockIdx.x;
  int pidx = vis[b*NVIS + i];
  int gy = pidx / 50, gx = pidx - gy*50;
  #pragma unroll
  for (int k=0;k<3;k++){
    int d = threadIdx.x + k*256;
    int c = d >> 8, rr = d & 255, py = rr >> 4, px = rr & 15;
    float v = x[(((size_t)b*3 + c)*800 + gy*16 + py)*800 + gx*16 + px]
            + enc_pos[(size_t)i*768 + d];
    size_t off = (size_t)(b*NVIS + i)*768 + d;
    xe[off] = v; xeb[off] = f2bf(v);
  }
}

// rank(p) = #{j : vis[j] < p}  (reproduces full.at[b, sort(vis)].set(h))
__global__ __launch_bounds__(256) void rank_kernel(const int* __restrict__ vis,
    int* __restrict__ rnk){
  int b = blockIdx.y; int i = blockIdx.x*256 + threadIdx.x;
  if (i >= NVIS) return;
  int p = vis[b*NVIS + i]; int c = 0;
  for (int j=0;j<NVIS;j++) c += (vis[b*NVIS + j] < p) ? 1 : 0;
  rnk[b*NVIS + i] = c;
}

__global__ __launch_bounds__(256) void dec_init_kernel(const float* __restrict__ mask_token,
    const float* __restrict__ dec_pos, float* __restrict__ xd, short* __restrict__ xdb){
  int row = blockIdx.x;                 // b*2500 + p
  int p = row % NPATCH;
  #pragma unroll
  for (int k=0;k<3;k++){
    int c = threadIdx.x + k*256;
    float v = mask_token[c] + dec_pos[(size_t)p*768 + c];
    size_t off = (size_t)row*768 + c;
    xd[off] = v; xdb[off] = f2bf(v);
  }
}

__global__ __launch_bounds__(256) void scatter_kernel(const int* __restrict__ vis,
    const int* __restrict__ rnk, const float* __restrict__ xe,
    const float* __restrict__ dec_pos, float* __restrict__ xd, short* __restrict__ xdb){
  int b = blockIdx.y, i = blockIdx.x;
  int p = vis[b*NVIS+i]; int r = rnk[b*NVIS+i];
  #pragma unroll
  for (int k=0;k<3;k++){
    int c = threadIdx.x + k*256;
    float v = xe[(size_t)(b*NVIS + r)*768 + c] + dec_pos[(size_t)p*768 + c];
    size_t off = (size_t)(b*NPATCH + p)*768 + c;
    xd[off] = v; xdb[off] = f2bf(v);
  }
}

// ---------------------------------------------------------------------------
// host side
// ---------------------------------------------------------------------------
static void run_block(hipStream_t stream, float* xf, short* xb, int M, int N, int NT,
                      int NS,
                      const short* wqkvT, const float* qkv_b, const short* woutT,
                      const float* out_b, const short* w1T, const float* b1,
                      const short* w2T, const float* b2,
                      const float* g1, const float* be1, const float* g2, const float* be2,
                      short* qkvb, short* vt, short* aob, short* ffnb,
                      float* tmp, float* tmp2, float* pmb, float* plb){
  int mt = (M + 127)/128;
  int mtq = (N + 63)/64;
  int TPS = (NT + NS - 1)/NS;
  float* poA = tmp;            // splits [0, NS/2)
  float* poB = (float*)ffnb;   // splits [NS/2, NS)
  gemm_kernel<0><<<dim3(mt, 18, 1), 256, 0, stream>>>(xb, wqkvT, qkv_b, qkvb,
                                                      nullptr, nullptr, M, 2304, 768, 12);
  vtrans_kernel<<<dim3(NT*2, 3, 16), 256, 0, stream>>>(qkvb, vt, N);
  attn_kernel<<<dim3(mtq, 16, NS), 256, 0, stream>>>(qkvb, vt, poA, poB, pmb, plb,
                                                     N, NT, TPS, NS/2);
  attn_merge_kernel<<<2*N, 256, 0, stream>>>(poA, poB, pmb, plb, aob, N, NS);
  gemm_kernel<1><<<dim3(mt, 6, 2), 256, 0, stream>>>(aob, woutT, out_b, nullptr,
                                                     tmp, tmp2, M, 768, 768, 6);
  ln_kernel<<<M, 256, 0, stream>>>(xf, tmp, tmp2, g1, be1, xf, xb);
  gemm_kernel<2><<<dim3(mt, 16, 1), 256, 0, stream>>>(xb, w1T, b1, ffnb,
                                                      nullptr, nullptr, M, 2048, 768, 12);
  gemm_kernel<1><<<dim3(mt, 6, 2), 256, 0, stream>>>(ffnb, w2T, b2, nullptr,
                                                     tmp, tmp2, M, 768, 2048, 16);
  ln_kernel<<<M, 256, 0, stream>>>(xf, tmp, tmp2, g2, be2, xf, xb);
}

extern "C" void kernel_launch(void* const* d_in, const int* in_sizes, int n_in,
                              void* d_out, int out_size, void* d_ws, size_t ws_size,
                              hipStream_t stream){
  const float* x        = (const float*)d_in[0];
  const int*   vis      = (const int*)d_in[1];
  const float* eqkv_w   = (const float*)d_in[3];
  const float* eqkv_b   = (const float*)d_in[4];
  const float* eout_w   = (const float*)d_in[5];
  const float* eout_b   = (const float*)d_in[6];
  const float* ew1      = (const float*)d_in[7];
  const float* eb1      = (const float*)d_in[8];
  const float* ew2      = (const float*)d_in[9];
  const float* eb2      = (const float*)d_in[10];
  const float* eg1      = (const float*)d_in[11];
  const float* ebe1     = (const float*)d_in[12];
  const float* eg2      = (const float*)d_in[13];
  const float* ebe2     = (const float*)d_in[14];
  const float* dqkv_w   = (const float*)d_in[15];
  const float* dqkv_b   = (const float*)d_in[16];
  const float* dout_w   = (const float*)d_in[17];
  const float* dout_b   = (const float*)d_in[18];
  const float* dw1      = (const float*)d_in[19];
  const float* db1      = (const float*)d_in[20];
  const float* dw2      = (const float*)d_in[21];
  const float* db2      = (const float*)d_in[22];
  const float* dg1      = (const float*)d_in[23];
  const float* dbe1     = (const float*)d_in[24];
  const float* dg2      = (const float*)d_in[25];
  const float* dbe2     = (const float*)d_in[26];
  const float* fout_w   = (const float*)d_in[27];
  const float* fout_b   = (const float*)d_in[28];
  const float* mask_tok = (const float*)d_in[29];
  const float* enc_posp = (const float*)d_in[30];
  const float* dec_posp = (const float*)d_in[31];

  char* p = (char*)d_ws;
  auto alloc = [&](size_t bytes)->char*{ char* r = p; p += (bytes + 255) & ~(size_t)255; return r; };

  const float* qkvw_s[2] = {eqkv_w, dqkv_w};
  const float* outw_s[2] = {eout_w, dout_w};
  const float* w1_s[2]   = {ew1, dw1};
  const float* w2_s[2]   = {ew2, dw2};

  short *wq[2][2], *wo[2][2], *w1t[2][2], *w2t[2][2];
  TJobs jobs; int jidx = 0; int tbase = 0;
  auto addJob = [&](const float* src, short* dst, int K, int N){
    jobs.j[jidx].src = src; jobs.j[jidx].dst = dst; jobs.j[jidx].K = K; jobs.j[jidx].N = N;
    jobs.j[jidx].tile_base = tbase; jobs.j[jidx].tiles_x = N/32;
    tbase += (K/32)*(N/32); jidx++;
  };
  for (int s=0;s<2;s++)
    for (int i=0;i<2;i++){
      wq[s][i]  = (short*)alloc((size_t)2304*768*2);
      addJob(qkvw_s[s] + (size_t)i*768*2304, wq[s][i], 768, 2304);
      wo[s][i]  = (short*)alloc((size_t)768*768*2);
      addJob(outw_s[s] + (size_t)i*768*768, wo[s][i], 768, 768);
      w1t[s][i] = (short*)alloc((size_t)2048*768*2);
      addJob(w1_s[s] + (size_t)i*768*2048, w1t[s][i], 768, 2048);
      w2t[s][i] = (short*)alloc((size_t)768*2048*2);
      addJob(w2_s[s] + (size_t)i*2048*768, w2t[s][i], 2048, 768);
    }
  short* wfin = (short*)alloc((size_t)768*768*2);
  addJob(fout_w, wfin, 768, 768);
  int total_tiles = tbase;   // 22080

  float* xe   = (float*)alloc((size_t)2500*768*4);
  short* xeb  = (short*)alloc((size_t)2500*768*2);
  float* xd   = (float*)alloc((size_t)5000*768*4);
  short* xdb  = (short*)alloc((size_t)5000*768*2);
  short* qkvb = (short*)alloc((size_t)5000*2304*2);
  short* vt   = (short*)alloc((size_t)16*96*NPADV*2);
  short* aob  = (short*)alloc((size_t)5000*768*2);
  short* ffnb = (short*)alloc((size_t)5000*2048*2);
  float* tmp  = (float*)alloc((size_t)5000*768*4);
  float* pmb  = (float*)alloc((size_t)4*2*8*2560*4);
  float* plb  = (float*)alloc((size_t)4*2*8*2560*4);
  int*   rnk  = (int*)alloc((size_t)2*NVIS*4);
  float* tmp2 = (float*)qkvb;   // 23MB >= 15.4MB; qkvb dead after attn+merge

  transpose_all_kernel<<<total_tiles, 256, 0, stream>>>(jobs);
  patchify_kernel<<<dim3(NVIS, NBATCH), 256, 0, stream>>>(x, vis, enc_posp, xe, xeb);
  rank_kernel<<<dim3((NVIS+255)/256, NBATCH), 256, 0, stream>>>(vis, rnk);

  for (int i=0;i<2;i++)
    run_block(stream, xe, xeb, 2500, 1250, 20, 4,
              wq[0][i], eqkv_b + i*2304, wo[0][i], eout_b + i*768,
              w1t[0][i], eb1 + i*2048, w2t[0][i], eb2 + i*768,
              eg1 + i*768, ebe1 + i*768, eg2 + i*768, ebe2 + i*768,
              qkvb, vt, aob, ffnb, tmp, tmp2, pmb, plb);

  dec_init_kernel<<<NBATCH*NPATCH, 256, 0, stream>>>(mask_tok, dec_posp, xd, xdb);
  scatter_kernel<<<dim3(NVIS, NBATCH), 256, 0, stream>>>(vis, rnk, xe, dec_posp, xd, xdb);

  for (int i=0;i<2;i++)
    run_block(stream, xd, xdb, 5000, 2500, 40, 2,
              wq[1][i], dqkv_b + i*2304, wo[1][i], dout_b + i*768,
              w1t[1][i], db1 + i*2048, w2t[1][i], db2 + i*768,
              dg1 + i*768, dbe1 + i*768, dg2 + i*768, dbe2 + i*768,
              qkvb, vt, aob, ffnb, tmp, tmp2, pmb, plb);

  // final head: split-K=2 -> tmp/tmp2, then add
  gemm_kernel<1><<<dim3(40, 6, 2), 256, 0, stream>>>(xdb, wfin, fout_b, nullptr,
                                                     tmp, tmp2, 5000, 768, 768, 6);
  add2_kernel<<<2048, 256, 0, stream>>>(tmp, tmp2, (float*)d_out, 5000*768);
}